// Round 1
// baseline (156.954 us; speedup 1.0000x reference)
//
#include <hip/hip_runtime.h>

// MSMLTransformerLayer — f32 correctness-first baseline.
// B=2, N=4096, D=256, WIN=16, W=256. Only windows w<16 survive the output
// slice, so phi_q needs only tokens [0,256) per batch and att is 32 GEMMs
// of 256^3. phi = elu(elu(z)+1)+1 == elu(z)+2 since elu(z)+1 >= 0.

#define DIM 256
#define NTOK 4096
#define NBATCH 2
#define RD (NBATCH * NTOK * DIM) // 2,097,152 floats

__device__ __forceinline__ float silu_f(float z) { return z / (1.f + __expf(-z)); }
__device__ __forceinline__ float elu2_f(float z) { return z > 0.f ? z + 2.f : __expf(z) + 1.f; }

// ---------------- LayerNorm: one row per block, 256 threads ----------------
__global__ void ln_kernel(const float* __restrict__ X, const float* __restrict__ g,
                          const float* __restrict__ bb, float* __restrict__ Y) {
    const int row = blockIdx.x;
    const int tid = threadIdx.x;
    const size_t idx = (size_t)row * DIM + tid;
    float v = X[idx];
    float s1 = v, s2 = v * v;
    #pragma unroll
    for (int o = 32; o > 0; o >>= 1) {
        s1 += __shfl_down(s1, o);
        s2 += __shfl_down(s2, o);
    }
    __shared__ float red[10];
    const int wv = tid >> 6;
    if ((tid & 63) == 0) { red[wv] = s1; red[4 + wv] = s2; }
    __syncthreads();
    if (tid == 0) {
        float a = red[0] + red[1] + red[2] + red[3];
        float q = red[4] + red[5] + red[6] + red[7];
        float m = a * (1.f / DIM);
        float var = q * (1.f / DIM) - m * m;
        red[8] = m;
        red[9] = rsqrtf(var + 1e-5f);
    }
    __syncthreads();
    const float m = red[8], rs = red[9];
    Y[idx] = (v - m) * rs * g[tid] + bb[tid];
}

// final: out = LN(hid + h)
__global__ void final_ln_kernel(const float* __restrict__ HID, const float* __restrict__ H,
                                const float* __restrict__ g, const float* __restrict__ bb,
                                float* __restrict__ Y) {
    const int row = blockIdx.x;
    const int tid = threadIdx.x;
    const size_t idx = (size_t)row * DIM + tid;
    float v = HID[idx] + H[idx];
    float s1 = v, s2 = v * v;
    #pragma unroll
    for (int o = 32; o > 0; o >>= 1) {
        s1 += __shfl_down(s1, o);
        s2 += __shfl_down(s2, o);
    }
    __shared__ float red[10];
    const int wv = tid >> 6;
    if ((tid & 63) == 0) { red[wv] = s1; red[4 + wv] = s2; }
    __syncthreads();
    if (tid == 0) {
        float a = red[0] + red[1] + red[2] + red[3];
        float q = red[4] + red[5] + red[6] + red[7];
        float m = a * (1.f / DIM);
        float var = q * (1.f / DIM) - m * m;
        red[8] = m;
        red[9] = rsqrtf(var + 1e-5f);
    }
    __syncthreads();
    const float m = red[8], rs = red[9];
    Y[idx] = (v - m) * rs * g[tid] + bb[tid];
}

// ---------------- Generic GEMM: Y[r,c] = act(sum_k X[r,k]*W[c,k] + bias[c]) ----
// 64x64 block tile, 4x4 register tile, K-tile 16. ACT: 0 none, 1 silu, 2 elu+2.
// QMODE: row remap r -> (r>>8)*NTOK + (r&255) for the q projection (tokens
// [0,256) of each batch); Y stays compact at row r.
template<int ACT, int QMODE>
__global__ void gemm_act(const float* __restrict__ X, const float* __restrict__ W,
                         const float* __restrict__ bias, float* __restrict__ Y) {
    __shared__ __align__(16) float Xs[16][68];
    __shared__ __align__(16) float Ws[16][68];
    const int r0 = blockIdx.x * 64;
    const int c0 = blockIdx.y * 64;
    const int tid = threadIdx.x;
    const int tx = tid & 15, ty = tid >> 4;
    const int lk = tid & 15, lr = tid >> 4;
    float acc[4][4] = {};
    for (int kt = 0; kt < DIM; kt += 16) {
        #pragma unroll
        for (int p = 0; p < 4; ++p) {
            const int r = lr + p * 16;
            int gr = r0 + r;
            if (QMODE) gr = ((gr >> 8) * NTOK) + (gr & 255);
            Xs[lk][r] = X[(size_t)gr * DIM + kt + lk];
            Ws[lk][r] = W[(size_t)(c0 + r) * DIM + kt + lk];
        }
        __syncthreads();
        #pragma unroll
        for (int kk = 0; kk < 16; ++kk) {
            const float4 a4 = *(const float4*)&Xs[kk][ty * 4];
            const float4 b4 = *(const float4*)&Ws[kk][tx * 4];
            const float av[4] = {a4.x, a4.y, a4.z, a4.w};
            const float bw[4] = {b4.x, b4.y, b4.z, b4.w};
            #pragma unroll
            for (int i = 0; i < 4; ++i)
                #pragma unroll
                for (int j = 0; j < 4; ++j)
                    acc[i][j] += av[i] * bw[j];
        }
        __syncthreads();
    }
    #pragma unroll
    for (int i = 0; i < 4; ++i) {
        const int r = r0 + ty * 4 + i;
        float4 o;
        float* po = (float*)&o;
        #pragma unroll
        for (int j = 0; j < 4; ++j) {
            float z = acc[i][j] + bias[c0 + tx * 4 + j];
            if (ACT == 1) z = silu_f(z);
            else if (ACT == 2) z = elu2_f(z);
            po[j] = z;
        }
        *(float4*)&Y[(size_t)r * DIM + c0 + tx * 4] = o;
    }
}

// ---------------- KV: KV[b,m,c,d] = sum_w phi_k[b, w*16+m, c] * h[b, w*16+m, d]
// One (b,m) pair per blockIdx.x (32 total); 64x64 tile of the 256x256 output.
__global__ void kv_kernel(const float* __restrict__ phik, const float* __restrict__ H,
                          float* __restrict__ KV) {
    __shared__ __align__(16) float As[16][68];
    __shared__ __align__(16) float Bs[16][68];
    const int bm = blockIdx.x;
    const int b = bm >> 4, m = bm & 15;
    const int c0 = blockIdx.y * 64, d0 = blockIdx.z * 64;
    const int tid = threadIdx.x;
    const int tx = tid & 15, ty = tid >> 4;
    const int le = tid & 63, lw = tid >> 6;
    const float* baseK = phik + ((size_t)b * NTOK + m) * DIM;
    const float* baseV = H + ((size_t)b * NTOK + m) * DIM;
    float acc[4][4] = {};
    for (int kt = 0; kt < 256; kt += 16) { // over windows w
        #pragma unroll
        for (int p = 0; p < 4; ++p) {
            const int ww = lw + p * 4;
            const size_t roff = (size_t)(kt + ww) * 16 * DIM;
            As[ww][le] = baseK[roff + c0 + le];
            Bs[ww][le] = baseV[roff + d0 + le];
        }
        __syncthreads();
        #pragma unroll
        for (int kk = 0; kk < 16; ++kk) {
            const float4 a4 = *(const float4*)&As[kk][ty * 4];
            const float4 b4 = *(const float4*)&Bs[kk][tx * 4];
            const float av[4] = {a4.x, a4.y, a4.z, a4.w};
            const float bw[4] = {b4.x, b4.y, b4.z, b4.w};
            #pragma unroll
            for (int i = 0; i < 4; ++i)
                #pragma unroll
                for (int j = 0; j < 4; ++j)
                    acc[i][j] += av[i] * bw[j];
        }
        __syncthreads();
    }
    #pragma unroll
    for (int i = 0; i < 4; ++i) {
        const int c = c0 + ty * 4 + i;
        float4 o;
        o.x = acc[i][0]; o.y = acc[i][1]; o.z = acc[i][2]; o.w = acc[i][3];
        *(float4*)&KV[((size_t)bm * DIM + c) * DIM + d0 + tx * 4] = o;
    }
}

// ---------------- att: for (b,m): out[qr,d] = sum_c phiq[b,qr,c]*KV[b,m,c,d]
// then +p(b, qr>>4, qr&15, m), multiply by act_res at token t=qr*16+m (in place).
__global__ void att_kernel(const float* __restrict__ phiq, const float* __restrict__ KV,
                           const float* __restrict__ embed, const float* __restrict__ pw,
                           const float* __restrict__ pb, float* __restrict__ actres_ag) {
    __shared__ __align__(16) float As[16][68];
    __shared__ __align__(16) float Bs[16][68];
    const int bm = blockIdx.x;
    const int b = bm >> 4, m = bm & 15;
    const int q0 = blockIdx.y * 64, d0 = blockIdx.z * 64;
    const int tid = threadIdx.x;
    const int tx = tid & 15, ty = tid >> 4;
    const int lk = tid & 15, lr = tid >> 4;
    const int le = tid & 63, lw = tid >> 6;
    const float* Q = phiq + (size_t)b * 256 * DIM;
    const float* Kvm = KV + (size_t)bm * DIM * DIM;
    float acc[4][4] = {};
    for (int kt = 0; kt < DIM; kt += 16) { // over c
        #pragma unroll
        for (int p = 0; p < 4; ++p) {
            const int qr = lr + p * 16;
            As[lk][qr] = Q[(size_t)(q0 + qr) * DIM + kt + lk];
            const int kk = lw + p * 4;
            Bs[kk][le] = Kvm[(size_t)(kt + kk) * DIM + d0 + le];
        }
        __syncthreads();
        #pragma unroll
        for (int kk = 0; kk < 16; ++kk) {
            const float4 a4 = *(const float4*)&As[kk][ty * 4];
            const float4 b4 = *(const float4*)&Bs[kk][tx * 4];
            const float av[4] = {a4.x, a4.y, a4.z, a4.w};
            const float bw[4] = {b4.x, b4.y, b4.z, b4.w};
            #pragma unroll
            for (int i = 0; i < 4; ++i)
                #pragma unroll
                for (int j = 0; j < 4; ++j)
                    acc[i][j] += av[i] * bw[j];
        }
        __syncthreads();
    }
    const float pw0 = pw[0], pw1 = pw[1], pw2 = pw[2], pbv = pb[0];
    #pragma unroll
    for (int i = 0; i < 4; ++i) {
        const int qr = q0 + ty * 4 + i;
        const int w = qr >> 4, n = qr & 15;
        // embed_qk[1, b, w, n, m, 0..2]
        const float* e = embed + ((size_t)(((NBATCH + b) * 256 + w) * 16 + n) * 16 + m) * 3;
        const float pv = e[0] * pw0 + e[1] * pw1 + e[2] * pw2 + pbv;
        const int t = qr * 16 + m;
        const size_t off = ((size_t)b * NTOK + t) * DIM + d0 + tx * 4;
        const float4 ar = *(const float4*)&actres_ag[off];
        float4 o;
        o.x = (acc[i][0] + pv) * ar.x;
        o.y = (acc[i][1] + pv) * ar.y;
        o.z = (acc[i][2] + pv) * ar.z;
        o.w = (acc[i][3] + pv) * ar.w;
        *(float4*)&actres_ag[off] = o;
    }
}

extern "C" void kernel_launch(void* const* d_in, const int* in_sizes, int n_in,
                              void* d_out, int out_size, void* d_ws, size_t ws_size,
                              hipStream_t stream) {
    const float* x    = (const float*)d_in[0];
    const float* emb  = (const float*)d_in[1];
    const float* Wa   = (const float*)d_in[2];
    const float* ba   = (const float*)d_in[3];
    const float* lng  = (const float*)d_in[4];
    const float* lnb  = (const float*)d_in[5];
    const float* Wc   = (const float*)d_in[6];
    const float* bc   = (const float*)d_in[7];
    const float* Wq   = (const float*)d_in[8];
    const float* bq   = (const float*)d_in[9];
    const float* Wk   = (const float*)d_in[10];
    const float* bk   = (const float*)d_in[11];
    const float* pw   = (const float*)d_in[12];
    const float* pb   = (const float*)d_in[13];
    const float* Wl   = (const float*)d_in[14];
    const float* bl   = (const float*)d_in[15];
    const float* ng   = (const float*)d_in[16];
    const float* nb   = (const float*)d_in[17];

    float* ws   = (float*)d_ws;
    float* xn   = ws;            // LN(x); later reused as hid
    float* act  = ws + (size_t)RD;       // act_res; later ag = att*act_res (in place)
    float* h    = ws + 2 * (size_t)RD;
    float* phik = ws + 3 * (size_t)RD;
    float* kv   = ws + 4 * (size_t)RD;   // [b*16+m][c][d]
    float* phiq = ws + 5 * (size_t)RD;   // [b*256+t][c], 512x256

    const dim3 blk(256);
    const dim3 gemm_grid(128, 4);     // 8192 rows
    const dim3 q_grid(8, 4);          // 512 rows
    const dim3 bm_grid(32, 4, 4);     // (b,m) x 4x4 tiles of 256x256

    // 1. xn = LN(x)
    ln_kernel<<<8192, blk, 0, stream>>>(x, lng, lnb, xn);
    // 2. act_res = silu(x @ Wa^T + ba)
    gemm_act<1, 0><<<gemm_grid, blk, 0, stream>>>(x, Wa, ba, act);
    // 3. h = silu(xn @ Wc^T + bc)
    gemm_act<1, 0><<<gemm_grid, blk, 0, stream>>>(xn, Wc, bc, h);
    // 4. phi_k = elu(h @ Wk^T + bk) + 2   (all tokens)
    gemm_act<2, 0><<<gemm_grid, blk, 0, stream>>>(h, Wk, bk, phik);
    // 5. phi_q = elu(h @ Wq^T + bq) + 2   (tokens [0,256) per batch)
    gemm_act<2, 1><<<q_grid, blk, 0, stream>>>(h, Wq, bq, phiq);
    // 6. KV
    kv_kernel<<<bm_grid, blk, 0, stream>>>(phik, h, kv);
    // 7. ag = (phi_q @ KV + p) * act_res   (in place in `act`)
    att_kernel<<<bm_grid, blk, 0, stream>>>(phiq, kv, emb, pw, pb, act);
    // 8. hid = ag @ Wl^T + bl   (into xn buffer)
    gemm_act<0, 0><<<gemm_grid, blk, 0, stream>>>(act, Wl, bl, xn);
    // 9. out = LN(hid + h)
    final_ln_kernel<<<8192, blk, 0, stream>>>(xn, h, ng, nb, (float*)d_out);
}

// Round 2
// 94.402 us; speedup vs baseline: 1.6626x; 1.6626x over previous
//
#include <hip/hip_runtime.h>

// MSMLTransformerLayer — bf16 MFMA round.
// B=2, N=4096, D=256, WIN=16. Only windows w<16 survive the output slice ->
// phi_q needs tokens [0,256) per batch. phi = elu(z)+2. All GEMMs use
// v_mfma_f32_16x16x32_bf16 (f32 accum). KV is a TN-GEMM (reduce over window
// rows): scalar transposed LDS reads; its output is stored transposed
// kvT[b][m][d][c] so the att GEMM gets a K-contiguous B operand.

#define DIM 256
#define NTOK 4096

typedef __attribute__((ext_vector_type(8))) short short8;
typedef __attribute__((ext_vector_type(4))) short short4v;
typedef __attribute__((ext_vector_type(4))) float f32x4;

__device__ __forceinline__ float silu_f(float z) { return z / (1.f + __expf(-z)); }
__device__ __forceinline__ float elu2_f(float z) { return z > 0.f ? z + 2.f : __expf(z) + 1.f; }

__device__ __forceinline__ short f2bf(float f) {
    union { float f; unsigned u; } v; v.f = f;
    unsigned r = v.u + 0x7fffu + ((v.u >> 16) & 1u);
    return (short)(r >> 16);
}
__device__ __forceinline__ float bf2f(short s) {
    union { unsigned u; float f; } v; v.u = ((unsigned)(unsigned short)s) << 16;
    return v.f;
}

// ---------------- weight cast: 5 matrices of 256x256 f32 -> bf16 -------------
__global__ __launch_bounds__(256) void wcast(const float* __restrict__ A, const float* __restrict__ B,
                                             const float* __restrict__ C, const float* __restrict__ D,
                                             const float* __restrict__ E, short* __restrict__ out) {
    const int which = blockIdx.y;
    const float* src = which == 0 ? A : which == 1 ? B : which == 2 ? C : which == 3 ? D : E;
    short* dst = out + (size_t)which * 65536;
    const int i = (blockIdx.x * 256 + threadIdx.x) * 4;
    const float4 v = *(const float4*)(src + i);
    short4v s; s[0] = f2bf(v.x); s[1] = f2bf(v.y); s[2] = f2bf(v.z); s[3] = f2bf(v.w);
    *(short4v*)(dst + i) = s;
}

// ---------------- LN + cast: xn_bf = bf16(LN(x)), x_bf = bf16(x) -------------
__global__ __launch_bounds__(256) void ln_cast(const float* __restrict__ X, const float* __restrict__ g,
                                               const float* __restrict__ bb, short* __restrict__ XN,
                                               short* __restrict__ XB) {
    const int row = blockIdx.x, tid = threadIdx.x;
    const size_t idx = (size_t)row * DIM + tid;
    float v = X[idx];
    float s1 = v, s2 = v * v;
    #pragma unroll
    for (int o = 32; o > 0; o >>= 1) { s1 += __shfl_down(s1, o); s2 += __shfl_down(s2, o); }
    __shared__ float red[10];
    const int wv = tid >> 6;
    if ((tid & 63) == 0) { red[wv] = s1; red[4 + wv] = s2; }
    __syncthreads();
    if (tid == 0) {
        float a = red[0] + red[1] + red[2] + red[3];
        float q = red[4] + red[5] + red[6] + red[7];
        float m = a * (1.f / DIM);
        red[8] = m; red[9] = rsqrtf(q * (1.f / DIM) - m * m + 1e-5f);
    }
    __syncthreads();
    XN[idx] = f2bf((v - red[8]) * red[9] * g[tid] + bb[tid]);
    XB[idx] = f2bf(v);
}

// ---------------- final: out = LN(hid + h) -----------------------------------
__global__ __launch_bounds__(256) void final_ln(const float* __restrict__ HID, const short* __restrict__ HB,
                                                const float* __restrict__ g, const float* __restrict__ bb,
                                                float* __restrict__ Y) {
    const int row = blockIdx.x, tid = threadIdx.x;
    const size_t idx = (size_t)row * DIM + tid;
    float v = HID[idx] + bf2f(HB[idx]);
    float s1 = v, s2 = v * v;
    #pragma unroll
    for (int o = 32; o > 0; o >>= 1) { s1 += __shfl_down(s1, o); s2 += __shfl_down(s2, o); }
    __shared__ float red[10];
    const int wv = tid >> 6;
    if ((tid & 63) == 0) { red[wv] = s1; red[4 + wv] = s2; }
    __syncthreads();
    if (tid == 0) {
        float a = red[0] + red[1] + red[2] + red[3];
        float q = red[4] + red[5] + red[6] + red[7];
        float m = a * (1.f / DIM);
        red[8] = m; red[9] = rsqrtf(q * (1.f / DIM) - m * m + 1e-5f);
    }
    __syncthreads();
    Y[idx] = (v - red[8]) * red[9] * g[tid] + bb[tid];
}

// ---------------- MFMA GEMM: Y[r][c] = act(sum_k X[r][k] W[c][k] + b[c]) -----
// Block tile 128(M)x64(N), K=256 in 4 steps of 64. 4 waves as 2Mx2N, wave
// tile 64x32. ACT: 0 none, 1 silu, 2 elu+2. QMODE: X row remap for phi_q.
// OUTF32: store f32 else bf16.
template<int ACT, int QMODE, int OUTF32>
__global__ __launch_bounds__(256) void gemm_mfma(const short* __restrict__ X, const short* __restrict__ W,
                                                 const float* __restrict__ bias, void* __restrict__ Yv) {
    __shared__ __align__(16) short Xs[128 * 72];
    __shared__ __align__(16) short Ws[64 * 72];
    const int tid = threadIdx.x;
    const int wv = tid >> 6, l = tid & 63;
    const int lr = l & 15, lk = l >> 4;
    const int r0 = blockIdx.x * 128, c0 = blockIdx.y * 64;
    const int wm = (wv >> 1) * 64, wn = (wv & 1) * 32;
    f32x4 acc[4][2];
    #pragma unroll
    for (int i = 0; i < 4; ++i)
        #pragma unroll
        for (int j = 0; j < 2; ++j) acc[i][j] = (f32x4){0.f, 0.f, 0.f, 0.f};

    const int sr = tid >> 3, sc = (tid & 7) * 8;
    for (int kt = 0; kt < DIM; kt += 64) {
        #pragma unroll
        for (int p = 0; p < 4; ++p) {
            const int row = sr + p * 32;
            int grow = r0 + row;
            if (QMODE) grow = ((grow >> 8) << 12) + (grow & 255);
            *(short8*)&Xs[row * 72 + sc] = *(const short8*)(X + (size_t)grow * DIM + kt + sc);
        }
        #pragma unroll
        for (int p = 0; p < 2; ++p) {
            const int row = sr + p * 32;
            *(short8*)&Ws[row * 72 + sc] = *(const short8*)(W + (size_t)(c0 + row) * DIM + kt + sc);
        }
        __syncthreads();
        #pragma unroll
        for (int kc = 0; kc < 2; ++kc) {
            short8 af[4], bf_[2];
            #pragma unroll
            for (int mi = 0; mi < 4; ++mi)
                af[mi] = *(const short8*)&Xs[(wm + mi * 16 + lr) * 72 + kc * 32 + lk * 8];
            #pragma unroll
            for (int ni = 0; ni < 2; ++ni)
                bf_[ni] = *(const short8*)&Ws[(wn + ni * 16 + lr) * 72 + kc * 32 + lk * 8];
            #pragma unroll
            for (int mi = 0; mi < 4; ++mi)
                #pragma unroll
                for (int ni = 0; ni < 2; ++ni)
                    acc[mi][ni] = __builtin_amdgcn_mfma_f32_16x16x32_bf16(af[mi], bf_[ni], acc[mi][ni], 0, 0, 0);
        }
        __syncthreads();
    }
    #pragma unroll
    for (int mi = 0; mi < 4; ++mi) {
        #pragma unroll
        for (int ni = 0; ni < 2; ++ni) {
            const int c = c0 + wn + ni * 16 + lr;
            const float bv = bias[c];
            #pragma unroll
            for (int i = 0; i < 4; ++i) {
                const int r = r0 + wm + mi * 16 + lk * 4 + i;
                float z = acc[mi][ni][i] + bv;
                if (ACT == 1) z = silu_f(z);
                else if (ACT == 2) z = elu2_f(z);
                if (OUTF32) ((float*)Yv)[(size_t)r * DIM + c] = z;
                else ((short*)Yv)[(size_t)r * DIM + c] = f2bf(z);
            }
        }
    }
}

// ---------------- KV: kvT[b][m][d][c] = sum_w h[t][d] * phik[t][c], t=w*16+m -
// TN-GEMM: reduction over LDS rows -> scalar transposed fragment reads.
// Block: one (b,m), 64(d)x64(c) tile; 4 waves 2x2, wave tile 32x32.
__global__ __launch_bounds__(256) void kv_mfma(const short* __restrict__ HB, const short* __restrict__ PK,
                                               short* __restrict__ KVT) {
    __shared__ __align__(16) short Hs[64 * 68];
    __shared__ __align__(16) short Ps[64 * 68];
    const int tid = threadIdx.x;
    const int bm = blockIdx.x, b = bm >> 4, m = bm & 15;
    const int d0 = blockIdx.y * 64, c0 = blockIdx.z * 64;
    const int wv = tid >> 6, l = tid & 63;
    const int lr = l & 15, lk = l >> 4;
    const int wd = (wv >> 1) * 32, wc = (wv & 1) * 32;
    f32x4 acc[2][2];
    #pragma unroll
    for (int i = 0; i < 2; ++i)
        #pragma unroll
        for (int j = 0; j < 2; ++j) acc[i][j] = (f32x4){0.f, 0.f, 0.f, 0.f};

    const size_t hbase = (size_t)b * NTOK * DIM;
    const int sr = tid >> 3, sc = (tid & 7) * 8;
    for (int kt = 0; kt < 256; kt += 64) {  // windows
        #pragma unroll
        for (int p = 0; p < 2; ++p) {
            const int w = sr + p * 32;
            const size_t g = hbase + (size_t)((kt + w) * 16 + m) * DIM;
            short8 hv = *(const short8*)(HB + g + d0 + sc);
            short8 pv = *(const short8*)(PK + g + c0 + sc);
            *(short4v*)&Hs[w * 68 + sc]     = __builtin_shufflevector(hv, hv, 0, 1, 2, 3);
            *(short4v*)&Hs[w * 68 + sc + 4] = __builtin_shufflevector(hv, hv, 4, 5, 6, 7);
            *(short4v*)&Ps[w * 68 + sc]     = __builtin_shufflevector(pv, pv, 0, 1, 2, 3);
            *(short4v*)&Ps[w * 68 + sc + 4] = __builtin_shufflevector(pv, pv, 4, 5, 6, 7);
        }
        __syncthreads();
        #pragma unroll
        for (int kc = 0; kc < 2; ++kc) {
            const int kb = kc * 32 + lk * 8;
            short8 af[2], bf_[2];
            #pragma unroll
            for (int di = 0; di < 2; ++di)
                #pragma unroll
                for (int i = 0; i < 8; ++i)
                    af[di][i] = Hs[(kb + i) * 68 + wd + di * 16 + lr];
            #pragma unroll
            for (int ci = 0; ci < 2; ++ci)
                #pragma unroll
                for (int i = 0; i < 8; ++i)
                    bf_[ci][i] = Ps[(kb + i) * 68 + wc + ci * 16 + lr];
            #pragma unroll
            for (int di = 0; di < 2; ++di)
                #pragma unroll
                for (int ci = 0; ci < 2; ++ci)
                    acc[di][ci] = __builtin_amdgcn_mfma_f32_16x16x32_bf16(af[di], bf_[ci], acc[di][ci], 0, 0, 0);
        }
        __syncthreads();
    }
    #pragma unroll
    for (int di = 0; di < 2; ++di)
        #pragma unroll
        for (int ci = 0; ci < 2; ++ci)
            #pragma unroll
            for (int i = 0; i < 4; ++i) {
                const int d = d0 + wd + di * 16 + lk * 4 + i;
                const int c = c0 + wc + ci * 16 + lr;
                KVT[((size_t)bm * DIM + d) * DIM + c] = f2bf(acc[di][ci][i]);
            }
}

// ---------------- att: ag[b][t][d] = (phiq[qr]·KV[.,d] + p) * act_res --------
// Per (b,m): D[qr][d] = sum_c phiq[b*256+qr][c] * kvT[bm][d][c]. Block tile
// 128(q)x64(d). t = qr*16+m.
__global__ __launch_bounds__(256) void att_mfma(const short* __restrict__ PQ, const short* __restrict__ KVT,
                                                const float* __restrict__ emb, const float* __restrict__ pw,
                                                const float* __restrict__ pb, const float* __restrict__ AR,
                                                short* __restrict__ AG) {
    __shared__ __align__(16) short Qs[128 * 72];
    __shared__ __align__(16) short Ks[64 * 72];
    const int tid = threadIdx.x;
    const int bm = blockIdx.x, b = bm >> 4, m = bm & 15;
    const int q0 = blockIdx.y * 128, d0 = blockIdx.z * 64;
    const int wv = tid >> 6, l = tid & 63;
    const int lr = l & 15, lk = l >> 4;
    const int wm = (wv >> 1) * 64, wn = (wv & 1) * 32;
    f32x4 acc[4][2];
    #pragma unroll
    for (int i = 0; i < 4; ++i)
        #pragma unroll
        for (int j = 0; j < 2; ++j) acc[i][j] = (f32x4){0.f, 0.f, 0.f, 0.f};

    const int sr = tid >> 3, sc = (tid & 7) * 8;
    for (int kt = 0; kt < DIM; kt += 64) {
        #pragma unroll
        for (int p = 0; p < 4; ++p) {
            const int row = sr + p * 32;
            *(short8*)&Qs[row * 72 + sc] = *(const short8*)(PQ + (size_t)(b * 256 + q0 + row) * DIM + kt + sc);
        }
        #pragma unroll
        for (int p = 0; p < 2; ++p) {
            const int row = sr + p * 32;
            *(short8*)&Ks[row * 72 + sc] = *(const short8*)(KVT + ((size_t)bm * DIM + d0 + row) * DIM + kt + sc);
        }
        __syncthreads();
        #pragma unroll
        for (int kc = 0; kc < 2; ++kc) {
            short8 af[4], bf_[2];
            #pragma unroll
            for (int mi = 0; mi < 4; ++mi)
                af[mi] = *(const short8*)&Qs[(wm + mi * 16 + lr) * 72 + kc * 32 + lk * 8];
            #pragma unroll
            for (int ni = 0; ni < 2; ++ni)
                bf_[ni] = *(const short8*)&Ks[(wn + ni * 16 + lr) * 72 + kc * 32 + lk * 8];
            #pragma unroll
            for (int mi = 0; mi < 4; ++mi)
                #pragma unroll
                for (int ni = 0; ni < 2; ++ni)
                    acc[mi][ni] = __builtin_amdgcn_mfma_f32_16x16x32_bf16(af[mi], bf_[ni], acc[mi][ni], 0, 0, 0);
        }
        __syncthreads();
    }
    const float pw0 = pw[0], pw1 = pw[1], pw2 = pw[2], pbv = pb[0];
    #pragma unroll
    for (int mi = 0; mi < 4; ++mi) {
        #pragma unroll
        for (int i = 0; i < 4; ++i) {
            const int qr = q0 + wm + mi * 16 + lk * 4 + i;
            const int widx = qr >> 4, nidx = qr & 15;
            const float* e = emb + ((((size_t)(2 + b) * 256 + widx) * 16 + nidx) * 16 + m) * 3;
            const float pv = e[0] * pw0 + e[1] * pw1 + e[2] * pw2 + pbv;
            const int t = qr * 16 + m;
            #pragma unroll
            for (int ni = 0; ni < 2; ++ni) {
                const int d = d0 + wn + ni * 16 + lr;
                const size_t o = ((size_t)b * NTOK + t) * DIM + d;
                AG[o] = f2bf((acc[mi][ni][i] + pv) * AR[o]);
            }
        }
    }
}

extern "C" void kernel_launch(void* const* d_in, const int* in_sizes, int n_in,
                              void* d_out, int out_size, void* d_ws, size_t ws_size,
                              hipStream_t stream) {
    const float* x   = (const float*)d_in[0];
    const float* emb = (const float*)d_in[1];
    const float* Wa  = (const float*)d_in[2];
    const float* ba  = (const float*)d_in[3];
    const float* lng = (const float*)d_in[4];
    const float* lnb = (const float*)d_in[5];
    const float* Wc  = (const float*)d_in[6];
    const float* bc  = (const float*)d_in[7];
    const float* Wq  = (const float*)d_in[8];
    const float* bq  = (const float*)d_in[9];
    const float* Wk  = (const float*)d_in[10];
    const float* bk  = (const float*)d_in[11];
    const float* pw  = (const float*)d_in[12];
    const float* pb  = (const float*)d_in[13];
    const float* Wl  = (const float*)d_in[14];
    const float* bl  = (const float*)d_in[15];
    const float* ng  = (const float*)d_in[16];
    const float* nb  = (const float*)d_in[17];

    char* ws = (char*)d_ws;
    const size_t MB = 1024 * 1024;
    short* x_bf   = (short*)(ws + 0 * MB);
    short* xn_bf  = (short*)(ws + 4 * MB);
    short* h_bf   = (short*)(ws + 8 * MB);
    short* phik   = (short*)(ws + 12 * MB);
    short* phiq   = (short*)(ws + 16 * MB);
    short* kvT    = (short*)(ws + 17 * MB);
    short* ag     = (short*)(ws + 21 * MB);
    short* wbf    = (short*)(ws + 25 * MB);   // 5 x 65536
    float* act    = (float*)(ws + 26 * MB);
    float* hid    = (float*)(ws + 34 * MB);

    short* Wa_bf = wbf + 0 * 65536;
    short* Wc_bf = wbf + 1 * 65536;
    short* Wk_bf = wbf + 2 * 65536;
    short* Wq_bf = wbf + 3 * 65536;
    short* Wl_bf = wbf + 4 * 65536;

    const dim3 blk(256);
    wcast<<<dim3(64, 5), blk, 0, stream>>>(Wa, Wc, Wk, Wq, Wl, wbf);
    ln_cast<<<8192, blk, 0, stream>>>(x, lng, lnb, xn_bf, x_bf);
    gemm_mfma<1, 0, 1><<<dim3(64, 4), blk, 0, stream>>>(x_bf, Wa_bf, ba, act);    // act_res f32
    gemm_mfma<1, 0, 0><<<dim3(64, 4), blk, 0, stream>>>(xn_bf, Wc_bf, bc, h_bf);  // h bf16
    gemm_mfma<2, 0, 0><<<dim3(64, 4), blk, 0, stream>>>(h_bf, Wk_bf, bk, phik);   // phi_k
    gemm_mfma<2, 1, 0><<<dim3(4, 4), blk, 0, stream>>>(h_bf, Wq_bf, bq, phiq);    // phi_q (512 rows)
    kv_mfma<<<dim3(32, 4, 4), blk, 0, stream>>>(h_bf, phik, kvT);
    att_mfma<<<dim3(32, 2, 4), blk, 0, stream>>>(phiq, kvT, emb, pw, pb, act, ag);
    gemm_mfma<0, 0, 1><<<dim3(64, 4), blk, 0, stream>>>(ag, Wl_bf, bl, hid);      // hid f32
    final_ln<<<8192, blk, 0, stream>>>(hid, h_bf, ng, nb, (float*)d_out);
}

// Round 4
// 73.956 us; speedup vs baseline: 2.1223x; 1.2765x over previous
//
#include <hip/hip_runtime.h>

// MSMLTransformerLayer — 7 launches. Round-3's fused gemm_ln (type-punned LDS
// reuse) caused post-timing divergence -> reverted to the verified
// gemm (hid f32) + final_ln pair. Kept: prep fusion, dual/kq packing, bf16 act.

#define DIM 256
#define NTOK 4096

typedef __attribute__((ext_vector_type(8))) short short8;
typedef __attribute__((ext_vector_type(4))) short short4v;
typedef __attribute__((ext_vector_type(4))) float f32x4;

__device__ __forceinline__ float silu_f(float z) { return z / (1.f + __expf(-z)); }
__device__ __forceinline__ float elu2_f(float z) { return z > 0.f ? z + 2.f : __expf(z) + 1.f; }

__device__ __forceinline__ short f2bf(float f) {
    union { float f; unsigned u; } v; v.f = f;
    unsigned r = v.u + 0x7fffu + ((v.u >> 16) & 1u);
    return (short)(r >> 16);
}
__device__ __forceinline__ float bf2f(short s) {
    union { unsigned u; float f; } v; v.u = ((unsigned)(unsigned short)s) << 16;
    return v.f;
}

// ---------------- prep: blocks [0,8192) LN rows; [8192,8512) weight casts ----
__global__ __launch_bounds__(256) void prep_kernel(
        const float* __restrict__ X, const float* __restrict__ g, const float* __restrict__ bb,
        short* __restrict__ XN, short* __restrict__ XB,
        const float* __restrict__ Wa, const float* __restrict__ Wc, const float* __restrict__ Wk,
        const float* __restrict__ Wq, const float* __restrict__ Wl, short* __restrict__ wbf) {
    const int tid = threadIdx.x;
    if (blockIdx.x >= 8192) {
        const int bidx = blockIdx.x - 8192;
        const int which = bidx >> 6, sub = bidx & 63;
        const float* src = which == 0 ? Wa : which == 1 ? Wc : which == 2 ? Wk : which == 3 ? Wq : Wl;
        short* dst = wbf + (size_t)which * 65536;
        const int i = (sub * 256 + tid) * 4;
        const float4 v = *(const float4*)(src + i);
        short4v s; s[0] = f2bf(v.x); s[1] = f2bf(v.y); s[2] = f2bf(v.z); s[3] = f2bf(v.w);
        *(short4v*)(dst + i) = s;
        return;
    }
    const int row = blockIdx.x;
    const size_t idx = (size_t)row * DIM + tid;
    float v = X[idx];
    float s1 = v, s2 = v * v;
    #pragma unroll
    for (int o = 32; o > 0; o >>= 1) { s1 += __shfl_down(s1, o); s2 += __shfl_down(s2, o); }
    __shared__ float red[10];
    const int wv = tid >> 6;
    if ((tid & 63) == 0) { red[wv] = s1; red[4 + wv] = s2; }
    __syncthreads();
    if (tid == 0) {
        float a = red[0] + red[1] + red[2] + red[3];
        float q = red[4] + red[5] + red[6] + red[7];
        float m = a * (1.f / DIM);
        red[8] = m; red[9] = rsqrtf(q * (1.f / DIM) - m * m + 1e-5f);
    }
    __syncthreads();
    XN[idx] = f2bf((v - red[8]) * red[9] * g[tid] + bb[tid]);
    XB[idx] = f2bf(v);
}

// ---------------- generic MFMA GEMM body (verified round 2) ------------------
// Block tile 128x64, K=256 in 4 steps. 4 waves 2Mx2N, wave tile 64x32.
// ACT: 0 none, 1 silu, 2 elu+2. QMODE: X row remap. OUTF32: f32 store.
template<int ACT, int QMODE, int OUTF32>
__global__ __launch_bounds__(256) void gemm_mfma(const short* __restrict__ X, const short* __restrict__ W,
                                                 const float* __restrict__ bias, void* __restrict__ Yv) {
    __shared__ __align__(16) short Xs[128 * 72];
    __shared__ __align__(16) short Ws[64 * 72];
    const int tid = threadIdx.x;
    const int wv = tid >> 6, l = tid & 63;
    const int lr = l & 15, lk = l >> 4;
    const int r0 = blockIdx.x * 128, c0 = blockIdx.y * 64;
    const int wm = (wv >> 1) * 64, wn = (wv & 1) * 32;
    f32x4 acc[4][2];
    #pragma unroll
    for (int i = 0; i < 4; ++i)
        #pragma unroll
        for (int j = 0; j < 2; ++j) acc[i][j] = (f32x4){0.f, 0.f, 0.f, 0.f};
    const int sr = tid >> 3, sc = (tid & 7) * 8;
    for (int kt = 0; kt < DIM; kt += 64) {
        #pragma unroll
        for (int p = 0; p < 4; ++p) {
            const int row = sr + p * 32;
            int grow = r0 + row;
            if (QMODE) grow = ((grow >> 8) << 12) + (grow & 255);
            *(short8*)&Xs[row * 72 + sc] = *(const short8*)(X + (size_t)grow * DIM + kt + sc);
        }
        #pragma unroll
        for (int p = 0; p < 2; ++p) {
            const int row = sr + p * 32;
            *(short8*)&Ws[row * 72 + sc] = *(const short8*)(W + (size_t)(c0 + row) * DIM + kt + sc);
        }
        __syncthreads();
        #pragma unroll
        for (int kc = 0; kc < 2; ++kc) {
            short8 af[4], bfr[2];
            #pragma unroll
            for (int mi = 0; mi < 4; ++mi)
                af[mi] = *(const short8*)&Xs[(wm + mi * 16 + lr) * 72 + kc * 32 + lk * 8];
            #pragma unroll
            for (int ni = 0; ni < 2; ++ni)
                bfr[ni] = *(const short8*)&Ws[(wn + ni * 16 + lr) * 72 + kc * 32 + lk * 8];
            #pragma unroll
            for (int mi = 0; mi < 4; ++mi)
                #pragma unroll
                for (int ni = 0; ni < 2; ++ni)
                    acc[mi][ni] = __builtin_amdgcn_mfma_f32_16x16x32_bf16(af[mi], bfr[ni], acc[mi][ni], 0, 0, 0);
        }
        __syncthreads();
    }
    #pragma unroll
    for (int mi = 0; mi < 4; ++mi)
        #pragma unroll
        for (int ni = 0; ni < 2; ++ni) {
            const int c = c0 + wn + ni * 16 + lr;
            const float bv = bias[c];
            #pragma unroll
            for (int i = 0; i < 4; ++i) {
                const int r = r0 + wm + mi * 16 + lk * 4 + i;
                float z = acc[mi][ni][i] + bv;
                if (ACT == 1) z = silu_f(z);
                else if (ACT == 2) z = elu2_f(z);
                if (OUTF32) ((float*)Yv)[(size_t)r * DIM + c] = z;
                else ((short*)Yv)[(size_t)r * DIM + c] = f2bf(z);
            }
        }
}

// ---------------- dual GEMM (silu): z=0 act_res; z=1 h -----------------------
__global__ __launch_bounds__(256) void gemm_dual(
        const short* __restrict__ X0, const short* __restrict__ W0, const float* __restrict__ b0, short* __restrict__ Y0,
        const short* __restrict__ X1, const short* __restrict__ W1, const float* __restrict__ b1, short* __restrict__ Y1) {
    __shared__ __align__(16) short Xs[128 * 72];
    __shared__ __align__(16) short Ws[64 * 72];
    const int zz = blockIdx.z;
    const short* X = zz ? X1 : X0;
    const short* W = zz ? W1 : W0;
    const float* bias = zz ? b1 : b0;
    short* Y = zz ? Y1 : Y0;
    const int tid = threadIdx.x;
    const int wv = tid >> 6, l = tid & 63;
    const int lr = l & 15, lk = l >> 4;
    const int r0 = blockIdx.x * 128, c0 = blockIdx.y * 64;
    const int wm = (wv >> 1) * 64, wn = (wv & 1) * 32;
    f32x4 acc[4][2];
    #pragma unroll
    for (int i = 0; i < 4; ++i)
        #pragma unroll
        for (int j = 0; j < 2; ++j) acc[i][j] = (f32x4){0.f, 0.f, 0.f, 0.f};
    const int sr = tid >> 3, sc = (tid & 7) * 8;
    for (int kt = 0; kt < DIM; kt += 64) {
        #pragma unroll
        for (int p = 0; p < 4; ++p) {
            const int row = sr + p * 32;
            *(short8*)&Xs[row * 72 + sc] = *(const short8*)(X + (size_t)(r0 + row) * DIM + kt + sc);
        }
        #pragma unroll
        for (int p = 0; p < 2; ++p) {
            const int row = sr + p * 32;
            *(short8*)&Ws[row * 72 + sc] = *(const short8*)(W + (size_t)(c0 + row) * DIM + kt + sc);
        }
        __syncthreads();
        #pragma unroll
        for (int kc = 0; kc < 2; ++kc) {
            short8 af[4], bfr[2];
            #pragma unroll
            for (int mi = 0; mi < 4; ++mi)
                af[mi] = *(const short8*)&Xs[(wm + mi * 16 + lr) * 72 + kc * 32 + lk * 8];
            #pragma unroll
            for (int ni = 0; ni < 2; ++ni)
                bfr[ni] = *(const short8*)&Ws[(wn + ni * 16 + lr) * 72 + kc * 32 + lk * 8];
            #pragma unroll
            for (int mi = 0; mi < 4; ++mi)
                #pragma unroll
                for (int ni = 0; ni < 2; ++ni)
                    acc[mi][ni] = __builtin_amdgcn_mfma_f32_16x16x32_bf16(af[mi], bfr[ni], acc[mi][ni], 0, 0, 0);
        }
        __syncthreads();
    }
    #pragma unroll
    for (int mi = 0; mi < 4; ++mi)
        #pragma unroll
        for (int ni = 0; ni < 2; ++ni) {
            const int c = c0 + wn + ni * 16 + lr;
            const float bv = bias[c];
            #pragma unroll
            for (int i = 0; i < 4; ++i) {
                const int r = r0 + wm + mi * 16 + lk * 4 + i;
                Y[(size_t)r * DIM + c] = f2bf(silu_f(acc[mi][ni][i] + bv));
            }
        }
}

// ---------------- k/q GEMM (elu+2): bx<64 phik; bx>=64 phiq ------------------
__global__ __launch_bounds__(256) void gemm_kq(
        const short* __restrict__ H, const short* __restrict__ Wk, const float* __restrict__ bk, short* __restrict__ PK,
        const short* __restrict__ Wq, const float* __restrict__ bq, short* __restrict__ PQ) {
    __shared__ __align__(16) short Xs[128 * 72];
    __shared__ __align__(16) short Ws[64 * 72];
    const int bx = blockIdx.x;
    const bool isq = bx >= 64;
    const short* W = isq ? Wq : Wk;
    const float* bias = isq ? bq : bk;
    short* Y = isq ? PQ : PK;
    const int r0 = (isq ? bx - 64 : bx) * 128;
    const int c0 = blockIdx.y * 64;
    const int tid = threadIdx.x;
    const int wv = tid >> 6, l = tid & 63;
    const int lr = l & 15, lk = l >> 4;
    const int wm = (wv >> 1) * 64, wn = (wv & 1) * 32;
    f32x4 acc[4][2];
    #pragma unroll
    for (int i = 0; i < 4; ++i)
        #pragma unroll
        for (int j = 0; j < 2; ++j) acc[i][j] = (f32x4){0.f, 0.f, 0.f, 0.f};
    const int sr = tid >> 3, sc = (tid & 7) * 8;
    for (int kt = 0; kt < DIM; kt += 64) {
        #pragma unroll
        for (int p = 0; p < 4; ++p) {
            const int row = sr + p * 32;
            int grow = r0 + row;
            if (isq) grow = ((grow >> 8) << 12) + (grow & 255);
            *(short8*)&Xs[row * 72 + sc] = *(const short8*)(H + (size_t)grow * DIM + kt + sc);
        }
        #pragma unroll
        for (int p = 0; p < 2; ++p) {
            const int row = sr + p * 32;
            *(short8*)&Ws[row * 72 + sc] = *(const short8*)(W + (size_t)(c0 + row) * DIM + kt + sc);
        }
        __syncthreads();
        #pragma unroll
        for (int kc = 0; kc < 2; ++kc) {
            short8 af[4], bfr[2];
            #pragma unroll
            for (int mi = 0; mi < 4; ++mi)
                af[mi] = *(const short8*)&Xs[(wm + mi * 16 + lr) * 72 + kc * 32 + lk * 8];
            #pragma unroll
            for (int ni = 0; ni < 2; ++ni)
                bfr[ni] = *(const short8*)&Ws[(wn + ni * 16 + lr) * 72 + kc * 32 + lk * 8];
            #pragma unroll
            for (int mi = 0; mi < 4; ++mi)
                #pragma unroll
                for (int ni = 0; ni < 2; ++ni)
                    acc[mi][ni] = __builtin_amdgcn_mfma_f32_16x16x32_bf16(af[mi], bfr[ni], acc[mi][ni], 0, 0, 0);
        }
        __syncthreads();
    }
    #pragma unroll
    for (int mi = 0; mi < 4; ++mi)
        #pragma unroll
        for (int ni = 0; ni < 2; ++ni) {
            const int c = c0 + wn + ni * 16 + lr;
            const float bv = bias[c];
            #pragma unroll
            for (int i = 0; i < 4; ++i) {
                const int r = r0 + wm + mi * 16 + lk * 4 + i;
                Y[(size_t)r * DIM + c] = f2bf(elu2_f(acc[mi][ni][i] + bv));
            }
        }
}

// ---------------- KV: kvT[b][m][d][c] = sum_w h[t][d]*phik[t][c], t=w*16+m ---
__global__ __launch_bounds__(256) void kv_mfma(const short* __restrict__ HB, const short* __restrict__ PK,
                                               short* __restrict__ KVT) {
    __shared__ __align__(16) short Hs[64 * 68];
    __shared__ __align__(16) short Ps[64 * 68];
    const int tid = threadIdx.x;
    const int bm = blockIdx.x, b = bm >> 4, m = bm & 15;
    const int d0 = blockIdx.y * 64, c0 = blockIdx.z * 64;
    const int wv = tid >> 6, l = tid & 63;
    const int lr = l & 15, lk = l >> 4;
    const int wd = (wv >> 1) * 32, wc = (wv & 1) * 32;
    f32x4 acc[2][2];
    #pragma unroll
    for (int i = 0; i < 2; ++i)
        #pragma unroll
        for (int j = 0; j < 2; ++j) acc[i][j] = (f32x4){0.f, 0.f, 0.f, 0.f};
    const size_t hbase = (size_t)b * NTOK * DIM;
    const int sr = tid >> 3, sc = (tid & 7) * 8;
    for (int kt = 0; kt < 256; kt += 64) {
        #pragma unroll
        for (int p = 0; p < 2; ++p) {
            const int w = sr + p * 32;
            const size_t gg = hbase + (size_t)((kt + w) * 16 + m) * DIM;
            short8 hv = *(const short8*)(HB + gg + d0 + sc);
            short8 pv = *(const short8*)(PK + gg + c0 + sc);
            *(short4v*)&Hs[w * 68 + sc]     = __builtin_shufflevector(hv, hv, 0, 1, 2, 3);
            *(short4v*)&Hs[w * 68 + sc + 4] = __builtin_shufflevector(hv, hv, 4, 5, 6, 7);
            *(short4v*)&Ps[w * 68 + sc]     = __builtin_shufflevector(pv, pv, 0, 1, 2, 3);
            *(short4v*)&Ps[w * 68 + sc + 4] = __builtin_shufflevector(pv, pv, 4, 5, 6, 7);
        }
        __syncthreads();
        #pragma unroll
        for (int kc = 0; kc < 2; ++kc) {
            const int kb = kc * 32 + lk * 8;
            short8 af[2], bfr[2];
            #pragma unroll
            for (int di = 0; di < 2; ++di)
                #pragma unroll
                for (int i = 0; i < 8; ++i)
                    af[di][i] = Hs[(kb + i) * 68 + wd + di * 16 + lr];
            #pragma unroll
            for (int ci = 0; ci < 2; ++ci)
                #pragma unroll
                for (int i = 0; i < 8; ++i)
                    bfr[ci][i] = Ps[(kb + i) * 68 + wc + ci * 16 + lr];
            #pragma unroll
            for (int di = 0; di < 2; ++di)
                #pragma unroll
                for (int ci = 0; ci < 2; ++ci)
                    acc[di][ci] = __builtin_amdgcn_mfma_f32_16x16x32_bf16(af[di], bfr[ci], acc[di][ci], 0, 0, 0);
        }
        __syncthreads();
    }
    #pragma unroll
    for (int di = 0; di < 2; ++di)
        #pragma unroll
        for (int ci = 0; ci < 2; ++ci)
            #pragma unroll
            for (int i = 0; i < 4; ++i) {
                const int d = d0 + wd + di * 16 + lk * 4 + i;
                const int c = c0 + wc + ci * 16 + lr;
                KVT[((size_t)bm * DIM + d) * DIM + c] = f2bf(acc[di][ci][i]);
            }
}

// ---------------- att: ag = (phiq @ kvT^T + p) * act_res ---------------------
__global__ __launch_bounds__(256) void att_mfma(const short* __restrict__ PQ, const short* __restrict__ KVT,
                                                const float* __restrict__ emb, const float* __restrict__ pw,
                                                const float* __restrict__ pb, const short* __restrict__ AR,
                                                short* __restrict__ AG) {
    __shared__ __align__(16) short Qs[128 * 72];
    __shared__ __align__(16) short Ks[64 * 72];
    const int tid = threadIdx.x;
    const int bm = blockIdx.x, b = bm >> 4, m = bm & 15;
    const int q0 = blockIdx.y * 128, d0 = blockIdx.z * 64;
    const int wv = tid >> 6, l = tid & 63;
    const int lr = l & 15, lk = l >> 4;
    const int wm = (wv >> 1) * 64, wn = (wv & 1) * 32;
    f32x4 acc[4][2];
    #pragma unroll
    for (int i = 0; i < 4; ++i)
        #pragma unroll
        for (int j = 0; j < 2; ++j) acc[i][j] = (f32x4){0.f, 0.f, 0.f, 0.f};
    const int sr = tid >> 3, sc = (tid & 7) * 8;
    for (int kt = 0; kt < DIM; kt += 64) {
        #pragma unroll
        for (int p = 0; p < 4; ++p) {
            const int row = sr + p * 32;
            *(short8*)&Qs[row * 72 + sc] = *(const short8*)(PQ + (size_t)(b * 256 + q0 + row) * DIM + kt + sc);
        }
        #pragma unroll
        for (int p = 0; p < 2; ++p) {
            const int row = sr + p * 32;
            *(short8*)&Ks[row * 72 + sc] = *(const short8*)(KVT + ((size_t)bm * DIM + d0 + row) * DIM + kt + sc);
        }
        __syncthreads();
        #pragma unroll
        for (int kc = 0; kc < 2; ++kc) {
            short8 af[4], bfr[2];
            #pragma unroll
            for (int mi = 0; mi < 4; ++mi)
                af[mi] = *(const short8*)&Qs[(wm + mi * 16 + lr) * 72 + kc * 32 + lk * 8];
            #pragma unroll
            for (int ni = 0; ni < 2; ++ni)
                bfr[ni] = *(const short8*)&Ks[(wn + ni * 16 + lr) * 72 + kc * 32 + lk * 8];
            #pragma unroll
            for (int mi = 0; mi < 4; ++mi)
                #pragma unroll
                for (int ni = 0; ni < 2; ++ni)
                    acc[mi][ni] = __builtin_amdgcn_mfma_f32_16x16x32_bf16(af[mi], bfr[ni], acc[mi][ni], 0, 0, 0);
        }
        __syncthreads();
    }
    const float pw0 = pw[0], pw1 = pw[1], pw2 = pw[2], pbv = pb[0];
    #pragma unroll
    for (int mi = 0; mi < 4; ++mi)
        #pragma unroll
        for (int i = 0; i < 4; ++i) {
            const int qr = q0 + wm + mi * 16 + lk * 4 + i;
            const int widx = qr >> 4, nidx = qr & 15;
            const float* e = emb + ((((size_t)(2 + b) * 256 + widx) * 16 + nidx) * 16 + m) * 3;
            const float pv = e[0] * pw0 + e[1] * pw1 + e[2] * pw2 + pbv;
            const int t = qr * 16 + m;
            #pragma unroll
            for (int ni = 0; ni < 2; ++ni) {
                const int d = d0 + wn + ni * 16 + lr;
                const size_t o = ((size_t)b * NTOK + t) * DIM + d;
                AG[o] = f2bf((acc[mi][ni][i] + pv) * bf2f(AR[o]));
            }
        }
}

// ---------------- final: out = LN(hid + h) -----------------------------------
__global__ __launch_bounds__(256) void final_ln(const float* __restrict__ HID, const short* __restrict__ HB,
                                                const float* __restrict__ g, const float* __restrict__ bb,
                                                float* __restrict__ Y) {
    const int row = blockIdx.x, tid = threadIdx.x;
    const size_t idx = (size_t)row * DIM + tid;
    float v = HID[idx] + bf2f(HB[idx]);
    float s1 = v, s2 = v * v;
    #pragma unroll
    for (int o = 32; o > 0; o >>= 1) { s1 += __shfl_down(s1, o); s2 += __shfl_down(s2, o); }
    __shared__ float red[10];
    const int wv = tid >> 6;
    if ((tid & 63) == 0) { red[wv] = s1; red[4 + wv] = s2; }
    __syncthreads();
    if (tid == 0) {
        float a = red[0] + red[1] + red[2] + red[3];
        float q = red[4] + red[5] + red[6] + red[7];
        float m = a * (1.f / DIM);
        red[8] = m; red[9] = rsqrtf(q * (1.f / DIM) - m * m + 1e-5f);
    }
    __syncthreads();
    Y[idx] = (v - red[8]) * red[9] * g[tid] + bb[tid];
}

extern "C" void kernel_launch(void* const* d_in, const int* in_sizes, int n_in,
                              void* d_out, int out_size, void* d_ws, size_t ws_size,
                              hipStream_t stream) {
    const float* x   = (const float*)d_in[0];
    const float* emb = (const float*)d_in[1];
    const float* Wa  = (const float*)d_in[2];
    const float* ba  = (const float*)d_in[3];
    const float* lng = (const float*)d_in[4];
    const float* lnb = (const float*)d_in[5];
    const float* Wc  = (const float*)d_in[6];
    const float* bc  = (const float*)d_in[7];
    const float* Wq  = (const float*)d_in[8];
    const float* bq  = (const float*)d_in[9];
    const float* Wk  = (const float*)d_in[10];
    const float* bk  = (const float*)d_in[11];
    const float* pw  = (const float*)d_in[12];
    const float* pb  = (const float*)d_in[13];
    const float* Wl  = (const float*)d_in[14];
    const float* bl  = (const float*)d_in[15];
    const float* ng  = (const float*)d_in[16];
    const float* nb  = (const float*)d_in[17];

    char* ws = (char*)d_ws;
    const size_t MB = 1024 * 1024;
    short* x_bf   = (short*)(ws + 0 * MB);
    short* xn_bf  = (short*)(ws + 4 * MB);
    short* h_bf   = (short*)(ws + 8 * MB);
    short* phik   = (short*)(ws + 12 * MB);
    short* phiq   = (short*)(ws + 16 * MB);
    short* kvT    = (short*)(ws + 17 * MB);
    short* ag     = (short*)(ws + 21 * MB);
    short* wbf    = (short*)(ws + 25 * MB);   // 5 x 65536
    short* act_bf = (short*)(ws + 26 * MB);
    float* hid    = (float*)(ws + 30 * MB);   // 8 MB f32

    short* Wa_bf = wbf + 0 * 65536;
    short* Wc_bf = wbf + 1 * 65536;
    short* Wk_bf = wbf + 2 * 65536;
    short* Wq_bf = wbf + 3 * 65536;
    short* Wl_bf = wbf + 4 * 65536;

    const dim3 blk(256);
    prep_kernel<<<8512, blk, 0, stream>>>(x, lng, lnb, xn_bf, x_bf, Wa, Wc, Wk, Wq, Wl, wbf);
    gemm_dual<<<dim3(64, 4, 2), blk, 0, stream>>>(x_bf, Wa_bf, ba, act_bf,
                                                  xn_bf, Wc_bf, bc, h_bf);
    gemm_kq<<<dim3(68, 4), blk, 0, stream>>>(h_bf, Wk_bf, bk, phik, Wq_bf, bq, phiq);
    kv_mfma<<<dim3(32, 4, 4), blk, 0, stream>>>(h_bf, phik, kvT);
    att_mfma<<<dim3(32, 2, 4), blk, 0, stream>>>(phiq, kvT, emb, pw, pb, act_bf, ag);
    gemm_mfma<0, 0, 1><<<dim3(64, 4), blk, 0, stream>>>(ag, Wl_bf, bl, hid);
    final_ln<<<8192, blk, 0, stream>>>(hid, h_bf, ng, nb, (float*)d_out);
}

// Round 5
// 68.163 us; speedup vs baseline: 2.3026x; 1.0850x over previous
//
#include <hip/hip_runtime.h>

// MSMLTransformerLayer — 6 launches.
// prep(LN + wcast) -> gemm_dual(act from f32 x, h) -> gemm_kq -> kv -> att ->
// gemm_lnfused (lin GEMM + residual + final LN; register-resident LN stats,
// disjoint LDS regions only — no type-punned reuse, unlike failed round 3).

#define DIM 256
#define NTOK 4096

typedef __attribute__((ext_vector_type(8))) short short8;
typedef __attribute__((ext_vector_type(4))) short short4v;
typedef __attribute__((ext_vector_type(4))) float f32x4;

__device__ __forceinline__ float silu_f(float z) { return z / (1.f + __expf(-z)); }
__device__ __forceinline__ float elu2_f(float z) { return z > 0.f ? z + 2.f : __expf(z) + 1.f; }

__device__ __forceinline__ short f2bf(float f) {
    union { float f; unsigned u; } v; v.f = f;
    unsigned r = v.u + 0x7fffu + ((v.u >> 16) & 1u);
    return (short)(r >> 16);
}
__device__ __forceinline__ float bf2f(short s) {
    union { unsigned u; float f; } v; v.u = ((unsigned)(unsigned short)s) << 16;
    return v.f;
}

// ---------------- prep: blocks [0,8192) LN rows; [8192,8512) weight casts ----
__global__ __launch_bounds__(256) void prep_kernel(
        const float* __restrict__ X, const float* __restrict__ g, const float* __restrict__ bb,
        short* __restrict__ XN,
        const float* __restrict__ Wa, const float* __restrict__ Wc, const float* __restrict__ Wk,
        const float* __restrict__ Wq, const float* __restrict__ Wl, short* __restrict__ wbf) {
    const int tid = threadIdx.x;
    if (blockIdx.x >= 8192) {
        const int bidx = blockIdx.x - 8192;
        const int which = bidx >> 6, sub = bidx & 63;
        const float* src = which == 0 ? Wa : which == 1 ? Wc : which == 2 ? Wk : which == 3 ? Wq : Wl;
        short* dst = wbf + (size_t)which * 65536;
        const int i = (sub * 256 + tid) * 4;
        const float4 v = *(const float4*)(src + i);
        short4v s; s[0] = f2bf(v.x); s[1] = f2bf(v.y); s[2] = f2bf(v.z); s[3] = f2bf(v.w);
        *(short4v*)(dst + i) = s;
        return;
    }
    const int row = blockIdx.x;
    const size_t idx = (size_t)row * DIM + tid;
    float v = X[idx];
    float s1 = v, s2 = v * v;
    #pragma unroll
    for (int o = 32; o > 0; o >>= 1) { s1 += __shfl_down(s1, o); s2 += __shfl_down(s2, o); }
    __shared__ float red[10];
    const int wv = tid >> 6;
    if ((tid & 63) == 0) { red[wv] = s1; red[4 + wv] = s2; }
    __syncthreads();
    if (tid == 0) {
        float a = red[0] + red[1] + red[2] + red[3];
        float q = red[4] + red[5] + red[6] + red[7];
        float m = a * (1.f / DIM);
        red[8] = m; red[9] = rsqrtf(q * (1.f / DIM) - m * m + 1e-5f);
    }
    __syncthreads();
    XN[idx] = f2bf((v - red[8]) * red[9] * g[tid] + bb[tid]);
}

// ---------------- dual GEMM (silu): z=0 act_res (A = x f32, converted);
// z=1 h (A = xn bf16). Block tile 128x64, 4 waves 2Mx2N, wave tile 64x32. ----
__global__ __launch_bounds__(256) void gemm_dual(
        const float* __restrict__ XF, const short* __restrict__ W0, const float* __restrict__ b0, short* __restrict__ Y0,
        const short* __restrict__ XN, const short* __restrict__ W1, const float* __restrict__ b1, short* __restrict__ Y1) {
    __shared__ __align__(16) short Xs[128 * 72];
    __shared__ __align__(16) short Ws[64 * 72];
    const int zz = blockIdx.z;
    const short* W = zz ? W1 : W0;
    const float* bias = zz ? b1 : b0;
    short* Y = zz ? Y1 : Y0;
    const int tid = threadIdx.x;
    const int wv = tid >> 6, l = tid & 63;
    const int lr = l & 15, lk = l >> 4;
    const int r0 = blockIdx.x * 128, c0 = blockIdx.y * 64;
    const int wm = (wv >> 1) * 64, wn = (wv & 1) * 32;
    f32x4 acc[4][2];
    #pragma unroll
    for (int i = 0; i < 4; ++i)
        #pragma unroll
        for (int j = 0; j < 2; ++j) acc[i][j] = (f32x4){0.f, 0.f, 0.f, 0.f};
    const int sr = tid >> 3, sc = (tid & 7) * 8;
    for (int kt = 0; kt < DIM; kt += 64) {
        #pragma unroll
        for (int p = 0; p < 4; ++p) {
            const int row = sr + p * 32;
            if (zz) {
                *(short8*)&Xs[row * 72 + sc] = *(const short8*)(XN + (size_t)(r0 + row) * DIM + kt + sc);
            } else {
                const float* src = XF + (size_t)(r0 + row) * DIM + kt + sc;
                const float4 a = *(const float4*)src;
                const float4 b2 = *(const float4*)(src + 4);
                short8 s;
                s[0] = f2bf(a.x); s[1] = f2bf(a.y); s[2] = f2bf(a.z); s[3] = f2bf(a.w);
                s[4] = f2bf(b2.x); s[5] = f2bf(b2.y); s[6] = f2bf(b2.z); s[7] = f2bf(b2.w);
                *(short8*)&Xs[row * 72 + sc] = s;
            }
        }
        #pragma unroll
        for (int p = 0; p < 2; ++p) {
            const int row = sr + p * 32;
            *(short8*)&Ws[row * 72 + sc] = *(const short8*)(W + (size_t)(c0 + row) * DIM + kt + sc);
        }
        __syncthreads();
        #pragma unroll
        for (int kc = 0; kc < 2; ++kc) {
            short8 af[4], bfr[2];
            #pragma unroll
            for (int mi = 0; mi < 4; ++mi)
                af[mi] = *(const short8*)&Xs[(wm + mi * 16 + lr) * 72 + kc * 32 + lk * 8];
            #pragma unroll
            for (int ni = 0; ni < 2; ++ni)
                bfr[ni] = *(const short8*)&Ws[(wn + ni * 16 + lr) * 72 + kc * 32 + lk * 8];
            #pragma unroll
            for (int mi = 0; mi < 4; ++mi)
                #pragma unroll
                for (int ni = 0; ni < 2; ++ni)
                    acc[mi][ni] = __builtin_amdgcn_mfma_f32_16x16x32_bf16(af[mi], bfr[ni], acc[mi][ni], 0, 0, 0);
        }
        __syncthreads();
    }
    #pragma unroll
    for (int mi = 0; mi < 4; ++mi)
        #pragma unroll
        for (int ni = 0; ni < 2; ++ni) {
            const int c = c0 + wn + ni * 16 + lr;
            const float bv = bias[c];
            #pragma unroll
            for (int i = 0; i < 4; ++i) {
                const int r = r0 + wm + mi * 16 + lk * 4 + i;
                Y[(size_t)r * DIM + c] = f2bf(silu_f(acc[mi][ni][i] + bv));
            }
        }
}

// ---------------- k/q GEMM (elu+2): bx<64 phik; bx>=64 phiq ------------------
__global__ __launch_bounds__(256) void gemm_kq(
        const short* __restrict__ H, const short* __restrict__ Wk, const float* __restrict__ bk, short* __restrict__ PK,
        const short* __restrict__ Wq, const float* __restrict__ bq, short* __restrict__ PQ) {
    __shared__ __align__(16) short Xs[128 * 72];
    __shared__ __align__(16) short Ws[64 * 72];
    const int bx = blockIdx.x;
    const bool isq = bx >= 64;
    const short* W = isq ? Wq : Wk;
    const float* bias = isq ? bq : bk;
    short* Y = isq ? PQ : PK;
    const int r0 = (isq ? bx - 64 : bx) * 128;
    const int c0 = blockIdx.y * 64;
    const int tid = threadIdx.x;
    const int wv = tid >> 6, l = tid & 63;
    const int lr = l & 15, lk = l >> 4;
    const int wm = (wv >> 1) * 64, wn = (wv & 1) * 32;
    f32x4 acc[4][2];
    #pragma unroll
    for (int i = 0; i < 4; ++i)
        #pragma unroll
        for (int j = 0; j < 2; ++j) acc[i][j] = (f32x4){0.f, 0.f, 0.f, 0.f};
    const int sr = tid >> 3, sc = (tid & 7) * 8;
    for (int kt = 0; kt < DIM; kt += 64) {
        #pragma unroll
        for (int p = 0; p < 4; ++p) {
            const int row = sr + p * 32;
            int grow = r0 + row;
            if (isq) grow = ((grow >> 8) << 12) + (grow & 255);
            *(short8*)&Xs[row * 72 + sc] = *(const short8*)(H + (size_t)grow * DIM + kt + sc);
        }
        #pragma unroll
        for (int p = 0; p < 2; ++p) {
            const int row = sr + p * 32;
            *(short8*)&Ws[row * 72 + sc] = *(const short8*)(W + (size_t)(c0 + row) * DIM + kt + sc);
        }
        __syncthreads();
        #pragma unroll
        for (int kc = 0; kc < 2; ++kc) {
            short8 af[4], bfr[2];
            #pragma unroll
            for (int mi = 0; mi < 4; ++mi)
                af[mi] = *(const short8*)&Xs[(wm + mi * 16 + lr) * 72 + kc * 32 + lk * 8];
            #pragma unroll
            for (int ni = 0; ni < 2; ++ni)
                bfr[ni] = *(const short8*)&Ws[(wn + ni * 16 + lr) * 72 + kc * 32 + lk * 8];
            #pragma unroll
            for (int mi = 0; mi < 4; ++mi)
                #pragma unroll
                for (int ni = 0; ni < 2; ++ni)
                    acc[mi][ni] = __builtin_amdgcn_mfma_f32_16x16x32_bf16(af[mi], bfr[ni], acc[mi][ni], 0, 0, 0);
        }
        __syncthreads();
    }
    #pragma unroll
    for (int mi = 0; mi < 4; ++mi)
        #pragma unroll
        for (int ni = 0; ni < 2; ++ni) {
            const int c = c0 + wn + ni * 16 + lr;
            const float bv = bias[c];
            #pragma unroll
            for (int i = 0; i < 4; ++i) {
                const int r = r0 + wm + mi * 16 + lk * 4 + i;
                Y[(size_t)r * DIM + c] = f2bf(elu2_f(acc[mi][ni][i] + bv));
            }
        }
}

// ---------------- KV: kvT[b][m][d][c] = sum_w h[t][d]*phik[t][c], t=w*16+m ---
__global__ __launch_bounds__(256) void kv_mfma(const short* __restrict__ HB, const short* __restrict__ PK,
                                               short* __restrict__ KVT) {
    __shared__ __align__(16) short Hs[64 * 68];
    __shared__ __align__(16) short Ps[64 * 68];
    const int tid = threadIdx.x;
    const int bm = blockIdx.x, b = bm >> 4, m = bm & 15;
    const int d0 = blockIdx.y * 64, c0 = blockIdx.z * 64;
    const int wv = tid >> 6, l = tid & 63;
    const int lr = l & 15, lk = l >> 4;
    const int wd = (wv >> 1) * 32, wc = (wv & 1) * 32;
    f32x4 acc[2][2];
    #pragma unroll
    for (int i = 0; i < 2; ++i)
        #pragma unroll
        for (int j = 0; j < 2; ++j) acc[i][j] = (f32x4){0.f, 0.f, 0.f, 0.f};
    const size_t hbase = (size_t)b * NTOK * DIM;
    const int sr = tid >> 3, sc = (tid & 7) * 8;
    for (int kt = 0; kt < 256; kt += 64) {
        #pragma unroll
        for (int p = 0; p < 2; ++p) {
            const int w = sr + p * 32;
            const size_t gg = hbase + (size_t)((kt + w) * 16 + m) * DIM;
            short8 hv = *(const short8*)(HB + gg + d0 + sc);
            short8 pv = *(const short8*)(PK + gg + c0 + sc);
            *(short4v*)&Hs[w * 68 + sc]     = __builtin_shufflevector(hv, hv, 0, 1, 2, 3);
            *(short4v*)&Hs[w * 68 + sc + 4] = __builtin_shufflevector(hv, hv, 4, 5, 6, 7);
            *(short4v*)&Ps[w * 68 + sc]     = __builtin_shufflevector(pv, pv, 0, 1, 2, 3);
            *(short4v*)&Ps[w * 68 + sc + 4] = __builtin_shufflevector(pv, pv, 4, 5, 6, 7);
        }
        __syncthreads();
        #pragma unroll
        for (int kc = 0; kc < 2; ++kc) {
            const int kb = kc * 32 + lk * 8;
            short8 af[2], bfr[2];
            #pragma unroll
            for (int di = 0; di < 2; ++di)
                #pragma unroll
                for (int i = 0; i < 8; ++i)
                    af[di][i] = Hs[(kb + i) * 68 + wd + di * 16 + lr];
            #pragma unroll
            for (int ci = 0; ci < 2; ++ci)
                #pragma unroll
                for (int i = 0; i < 8; ++i)
                    bfr[ci][i] = Ps[(kb + i) * 68 + wc + ci * 16 + lr];
            #pragma unroll
            for (int di = 0; di < 2; ++di)
                #pragma unroll
                for (int ci = 0; ci < 2; ++ci)
                    acc[di][ci] = __builtin_amdgcn_mfma_f32_16x16x32_bf16(af[di], bfr[ci], acc[di][ci], 0, 0, 0);
        }
        __syncthreads();
    }
    #pragma unroll
    for (int di = 0; di < 2; ++di)
        #pragma unroll
        for (int ci = 0; ci < 2; ++ci)
            #pragma unroll
            for (int i = 0; i < 4; ++i) {
                const int d = d0 + wd + di * 16 + lk * 4 + i;
                const int c = c0 + wc + ci * 16 + lr;
                KVT[((size_t)bm * DIM + d) * DIM + c] = f2bf(acc[di][ci][i]);
            }
}

// ---------------- att: ag = (phiq @ kvT^T + p) * act_res ---------------------
__global__ __launch_bounds__(256) void att_mfma(const short* __restrict__ PQ, const short* __restrict__ KVT,
                                                const float* __restrict__ emb, const float* __restrict__ pw,
                                                const float* __restrict__ pb, const short* __restrict__ AR,
                                                short* __restrict__ AG) {
    __shared__ __align__(16) short Qs[128 * 72];
    __shared__ __align__(16) short Ks[64 * 72];
    const int tid = threadIdx.x;
    const int bm = blockIdx.x, b = bm >> 4, m = bm & 15;
    const int q0 = blockIdx.y * 128, d0 = blockIdx.z * 64;
    const int wv = tid >> 6, l = tid & 63;
    const int lr = l & 15, lk = l >> 4;
    const int wm = (wv >> 1) * 64, wn = (wv & 1) * 32;
    f32x4 acc[4][2];
    #pragma unroll
    for (int i = 0; i < 4; ++i)
        #pragma unroll
        for (int j = 0; j < 2; ++j) acc[i][j] = (f32x4){0.f, 0.f, 0.f, 0.f};
    const int sr = tid >> 3, sc = (tid & 7) * 8;
    for (int kt = 0; kt < DIM; kt += 64) {
        #pragma unroll
        for (int p = 0; p < 4; ++p) {
            const int row = sr + p * 32;
            *(short8*)&Qs[row * 72 + sc] = *(const short8*)(PQ + (size_t)(b * 256 + q0 + row) * DIM + kt + sc);
        }
        #pragma unroll
        for (int p = 0; p < 2; ++p) {
            const int row = sr + p * 32;
            *(short8*)&Ks[row * 72 + sc] = *(const short8*)(KVT + ((size_t)bm * DIM + d0 + row) * DIM + kt + sc);
        }
        __syncthreads();
        #pragma unroll
        for (int kc = 0; kc < 2; ++kc) {
            short8 af[4], bfr[2];
            #pragma unroll
            for (int mi = 0; mi < 4; ++mi)
                af[mi] = *(const short8*)&Qs[(wm + mi * 16 + lr) * 72 + kc * 32 + lk * 8];
            #pragma unroll
            for (int ni = 0; ni < 2; ++ni)
                bfr[ni] = *(const short8*)&Ks[(wn + ni * 16 + lr) * 72 + kc * 32 + lk * 8];
            #pragma unroll
            for (int mi = 0; mi < 4; ++mi)
                #pragma unroll
                for (int ni = 0; ni < 2; ++ni)
                    acc[mi][ni] = __builtin_amdgcn_mfma_f32_16x16x32_bf16(af[mi], bfr[ni], acc[mi][ni], 0, 0, 0);
        }
        __syncthreads();
    }
    const float pw0 = pw[0], pw1 = pw[1], pw2 = pw[2], pbv = pb[0];
    #pragma unroll
    for (int mi = 0; mi < 4; ++mi)
        #pragma unroll
        for (int i = 0; i < 4; ++i) {
            const int qr = q0 + wm + mi * 16 + lk * 4 + i;
            const int widx = qr >> 4, nidx = qr & 15;
            const float* e = emb + ((((size_t)(2 + b) * 256 + widx) * 16 + nidx) * 16 + m) * 3;
            const float pv = e[0] * pw0 + e[1] * pw1 + e[2] * pw2 + pbv;
            const int t = qr * 16 + m;
            #pragma unroll
            for (int ni = 0; ni < 2; ++ni) {
                const int d = d0 + wn + ni * 16 + lr;
                const size_t o = ((size_t)b * NTOK + t) * DIM + d;
                AG[o] = f2bf((acc[mi][ni][i] + pv) * bf2f(AR[o]));
            }
        }
}

// ---------------- fused lin GEMM + residual + final LN -----------------------
// Tile 32 rows x 256 (full) cols; 4 waves 2Mx2N, wave tile 16x128, M_rep=1,
// N_rep=8. LN stats in registers: shfl_xor over 16 lr-lanes, cross-wave
// combine through small dedicated LDS. All LDS regions disjoint.
__global__ __launch_bounds__(256) void gemm_lnfused(
        const short* __restrict__ AG, const short* __restrict__ WL, const float* __restrict__ bias,
        const short* __restrict__ HB, const float* __restrict__ g, const float* __restrict__ bb,
        float* __restrict__ Y) {
    __shared__ __align__(16) short As[32 * 72];
    __shared__ __align__(16) short Bs[256 * 72];
    __shared__ __align__(16) short Rs[32 * 264];
    __shared__ float s1buf[32][2];
    __shared__ float s2buf[32][2];
    const int tid = threadIdx.x;
    const int wv = tid >> 6, l = tid & 63;
    const int lr = l & 15, lk = l >> 4;
    const int r0 = blockIdx.x * 32;
    const int wm = (wv >> 1) * 16, wn = (wv & 1) * 128;
    f32x4 acc[8];
    #pragma unroll
    for (int i = 0; i < 8; ++i) acc[i] = (f32x4){0.f, 0.f, 0.f, 0.f};
    const int sr = tid >> 3, sc = (tid & 7) * 8;

    // stage residual rows (read under any later barrier)
    #pragma unroll
    for (int p = 0; p < 4; ++p) {
        const int chunk = tid + p * 256;           // 1024 chunks of 8
        const int row = chunk >> 5, cc = (chunk & 31) * 8;
        *(short8*)&Rs[row * 264 + cc] = *(const short8*)(HB + (size_t)(r0 + row) * DIM + cc);
    }

    for (int kt = 0; kt < DIM; kt += 64) {
        *(short8*)&As[sr * 72 + sc] = *(const short8*)(AG + (size_t)(r0 + sr) * DIM + kt + sc);
        #pragma unroll
        for (int p = 0; p < 8; ++p) {
            const int row = sr + p * 32;
            *(short8*)&Bs[row * 72 + sc] = *(const short8*)(WL + (size_t)row * DIM + kt + sc);
        }
        __syncthreads();
        #pragma unroll
        for (int kc = 0; kc < 2; ++kc) {
            const short8 af = *(const short8*)&As[(wm + lr) * 72 + kc * 32 + lk * 8];
            #pragma unroll
            for (int ni = 0; ni < 8; ++ni) {
                const short8 bfr = *(const short8*)&Bs[(wn + ni * 16 + lr) * 72 + kc * 32 + lk * 8];
                acc[ni] = __builtin_amdgcn_mfma_f32_16x16x32_bf16(af, bfr, acc[ni], 0, 0, 0);
            }
        }
        __syncthreads();
    }

    // z = acc + bias + residual; per-row partial sums in registers
    float s1[4] = {0.f, 0.f, 0.f, 0.f}, s2[4] = {0.f, 0.f, 0.f, 0.f};
    #pragma unroll
    for (int ni = 0; ni < 8; ++ni) {
        const int col = wn + ni * 16 + lr;
        const float bv = bias[col];
        #pragma unroll
        for (int i = 0; i < 4; ++i) {
            const int row = wm + lk * 4 + i;
            const float z = acc[ni][i] + bv + bf2f(Rs[row * 264 + col]);
            acc[ni][i] = z;
            s1[i] += z; s2[i] += z * z;
        }
    }
    #pragma unroll
    for (int o = 1; o < 16; o <<= 1) {
        #pragma unroll
        for (int i = 0; i < 4; ++i) {
            s1[i] += __shfl_xor(s1[i], o);
            s2[i] += __shfl_xor(s2[i], o);
        }
    }
    if (lr == 0) {
        #pragma unroll
        for (int i = 0; i < 4; ++i) {
            const int row = wm + lk * 4 + i;
            s1buf[row][wv & 1] = s1[i];
            s2buf[row][wv & 1] = s2[i];
        }
    }
    __syncthreads();
    float mean[4], rstd[4];
    #pragma unroll
    for (int i = 0; i < 4; ++i) {
        const int row = wm + lk * 4 + i;
        const float t1 = s1buf[row][0] + s1buf[row][1];
        const float t2 = s2buf[row][0] + s2buf[row][1];
        const float mm = t1 * (1.f / DIM);
        mean[i] = mm;
        rstd[i] = rsqrtf(t2 * (1.f / DIM) - mm * mm + 1e-5f);
    }
    #pragma unroll
    for (int ni = 0; ni < 8; ++ni) {
        const int col = wn + ni * 16 + lr;
        const float gv = g[col], bv2 = bb[col];
        #pragma unroll
        for (int i = 0; i < 4; ++i) {
            const int row = wm + lk * 4 + i;
            Y[(size_t)(r0 + row) * DIM + col] = (acc[ni][i] - mean[i]) * rstd[i] * gv + bv2;
        }
    }
}

extern "C" void kernel_launch(void* const* d_in, const int* in_sizes, int n_in,
                              void* d_out, int out_size, void* d_ws, size_t ws_size,
                              hipStream_t stream) {
    const float* x   = (const float*)d_in[0];
    const float* emb = (const float*)d_in[1];
    const float* Wa  = (const float*)d_in[2];
    const float* ba  = (const float*)d_in[3];
    const float* lng = (const float*)d_in[4];
    const float* lnb = (const float*)d_in[5];
    const float* Wc  = (const float*)d_in[6];
    const float* bc  = (const float*)d_in[7];
    const float* Wq  = (const float*)d_in[8];
    const float* bq  = (const float*)d_in[9];
    const float* Wk  = (const float*)d_in[10];
    const float* bk  = (const float*)d_in[11];
    const float* pw  = (const float*)d_in[12];
    const float* pb  = (const float*)d_in[13];
    const float* Wl  = (const float*)d_in[14];
    const float* bl  = (const float*)d_in[15];
    const float* ng  = (const float*)d_in[16];
    const float* nb  = (const float*)d_in[17];

    char* ws = (char*)d_ws;
    const size_t MB = 1024 * 1024;
    short* xn_bf  = (short*)(ws + 0 * MB);
    short* h_bf   = (short*)(ws + 4 * MB);
    short* phik   = (short*)(ws + 8 * MB);
    short* phiq   = (short*)(ws + 12 * MB);
    short* kvT    = (short*)(ws + 13 * MB);
    short* ag     = (short*)(ws + 17 * MB);
    short* wbf    = (short*)(ws + 21 * MB);   // 5 x 65536
    short* act_bf = (short*)(ws + 22 * MB);

    short* Wa_bf = wbf + 0 * 65536;
    short* Wc_bf = wbf + 1 * 65536;
    short* Wk_bf = wbf + 2 * 65536;
    short* Wq_bf = wbf + 3 * 65536;
    short* Wl_bf = wbf + 4 * 65536;

    const dim3 blk(256);
    prep_kernel<<<8512, blk, 0, stream>>>(x, lng, lnb, xn_bf, Wa, Wc, Wk, Wq, Wl, wbf);
    gemm_dual<<<dim3(64, 4, 2), blk, 0, stream>>>(x, Wa_bf, ba, act_bf,
                                                  xn_bf, Wc_bf, bc, h_bf);
    gemm_kq<<<dim3(68, 4), blk, 0, stream>>>(h_bf, Wk_bf, bk, phik, Wq_bf, bq, phiq);
    kv_mfma<<<dim3(32, 4, 4), blk, 0, stream>>>(h_bf, phik, kvT);
    att_mfma<<<dim3(32, 2, 4), blk, 0, stream>>>(phiq, kvT, emb, pw, pb, act_bf, ag);
    gemm_lnfused<<<256, blk, 0, stream>>>(ag, Wl_bf, bl, h_bf, ng, nb, (float*)d_out);
}

// Round 7
// 58.635 us; speedup vs baseline: 2.6768x; 1.1625x over previous
//
#include <hip/hip_runtime.h>

// MSMLTransformerLayer — 4 launches.
// fused_dual (act + [LN-in-kernel] h; f32 weights staged) -> gemm_kq ->
// kv_mfma -> attlin (att GEMM + p + *act_res + lin GEMM + residual + final LN).
// Round-6 bug: kvT (4 MB at ws+9MB) overlapped act_bf (ws+11MB) -> act_bf
// moved to ws+13MB.

#define DIM 256
#define NTOK 4096

typedef __attribute__((ext_vector_type(8))) short short8;
typedef __attribute__((ext_vector_type(4))) short short4v;
typedef __attribute__((ext_vector_type(4))) float f32x4;

__device__ __forceinline__ float silu_f(float z) { return z / (1.f + __expf(-z)); }
__device__ __forceinline__ float elu2_f(float z) { return z > 0.f ? z + 2.f : __expf(z) + 1.f; }

__device__ __forceinline__ short f2bf(float f) {
    union { float f; unsigned u; } v; v.f = f;
    unsigned r = v.u + 0x7fffu + ((v.u >> 16) & 1u);
    return (short)(r >> 16);
}
__device__ __forceinline__ float bf2f(short s) {
    union { unsigned u; float f; } v; v.u = ((unsigned)(unsigned short)s) << 16;
    return v.f;
}
__device__ __forceinline__ short8 cvt8(const float* src) {
    const float4 a = *(const float4*)src;
    const float4 c = *(const float4*)(src + 4);
    short8 s;
    s[0] = f2bf(a.x); s[1] = f2bf(a.y); s[2] = f2bf(a.z); s[3] = f2bf(a.w);
    s[4] = f2bf(c.x); s[5] = f2bf(c.y); s[6] = f2bf(c.z); s[7] = f2bf(c.w);
    return s;
}

// ---------------- fused dual GEMM (silu). z=0: act = silu(x@Wa^T+ba);
// z=1: h = silu(LN(x)@Wc^T+bc), LN computed in-kernel (pass-1 row stats).
// Block tile 128x64, K=256 in 4 steps. 4 waves 2Mx2N, wave tile 64x32. -------
__global__ __launch_bounds__(256) void fused_dual(
        const float* __restrict__ XF,
        const float* __restrict__ W0f, const float* __restrict__ b0, short* __restrict__ Y0,
        const float* __restrict__ W1f, const float* __restrict__ b1, short* __restrict__ Y1,
        const float* __restrict__ G, const float* __restrict__ Bt) {
    __shared__ __align__(16) short Xs[128 * 72];
    __shared__ __align__(16) short Ws[64 * 72];
    __shared__ float stats[128][2];
    const int zz = blockIdx.z;
    const float* Wf = zz ? W1f : W0f;
    const float* bias = zz ? b1 : b0;
    short* Y = zz ? Y1 : Y0;
    const int tid = threadIdx.x;
    const int wv = tid >> 6, l = tid & 63;
    const int lr = l & 15, lk = l >> 4;
    const int r0 = blockIdx.x * 128, c0 = blockIdx.y * 64;
    const int wm = (wv >> 1) * 64, wn = (wv & 1) * 32;

    if (zz) {  // pass 1: LN stats for rows r0..r0+127 (2 threads per row)
        const int prow = tid >> 1, phalf = tid & 1;
        const float* src = XF + (size_t)(r0 + prow) * DIM + phalf * 128;
        float a1 = 0.f, a2 = 0.f;
        #pragma unroll 8
        for (int j = 0; j < 32; ++j) {
            const float4 v = *(const float4*)(src + j * 4);
            a1 += v.x + v.y + v.z + v.w;
            a2 += v.x * v.x + v.y * v.y + v.z * v.z + v.w * v.w;
        }
        a1 += __shfl_xor(a1, 1);
        a2 += __shfl_xor(a2, 1);
        if (!phalf) {
            const float mm = a1 * (1.f / DIM);
            stats[prow][0] = mm;
            stats[prow][1] = rsqrtf(a2 * (1.f / DIM) - mm * mm + 1e-5f);
        }
        __syncthreads();
    }

    f32x4 acc[4][2];
    #pragma unroll
    for (int i = 0; i < 4; ++i)
        #pragma unroll
        for (int j = 0; j < 2; ++j) acc[i][j] = (f32x4){0.f, 0.f, 0.f, 0.f};
    const int sr = tid >> 3, sc = (tid & 7) * 8;
    for (int kt = 0; kt < DIM; kt += 64) {
        float gv[8], bv[8];
        if (zz) {
            const float4 g1 = *(const float4*)(G + kt + sc);
            const float4 g2 = *(const float4*)(G + kt + sc + 4);
            const float4 t1 = *(const float4*)(Bt + kt + sc);
            const float4 t2 = *(const float4*)(Bt + kt + sc + 4);
            gv[0] = g1.x; gv[1] = g1.y; gv[2] = g1.z; gv[3] = g1.w;
            gv[4] = g2.x; gv[5] = g2.y; gv[6] = g2.z; gv[7] = g2.w;
            bv[0] = t1.x; bv[1] = t1.y; bv[2] = t1.z; bv[3] = t1.w;
            bv[4] = t2.x; bv[5] = t2.y; bv[6] = t2.z; bv[7] = t2.w;
        }
        #pragma unroll
        for (int p = 0; p < 4; ++p) {
            const int row = sr + p * 32;
            const float* src = XF + (size_t)(r0 + row) * DIM + kt + sc;
            const float4 a = *(const float4*)src;
            const float4 c = *(const float4*)(src + 4);
            float v[8] = {a.x, a.y, a.z, a.w, c.x, c.y, c.z, c.w};
            short8 s;
            if (zz) {
                const float mm = stats[row][0], rs = stats[row][1];
                #pragma unroll
                for (int j = 0; j < 8; ++j) s[j] = f2bf((v[j] - mm) * rs * gv[j] + bv[j]);
            } else {
                #pragma unroll
                for (int j = 0; j < 8; ++j) s[j] = f2bf(v[j]);
            }
            *(short8*)&Xs[row * 72 + sc] = s;
        }
        #pragma unroll
        for (int p = 0; p < 2; ++p) {
            const int row = sr + p * 32;
            *(short8*)&Ws[row * 72 + sc] = cvt8(Wf + (size_t)(c0 + row) * DIM + kt + sc);
        }
        __syncthreads();
        #pragma unroll
        for (int kc = 0; kc < 2; ++kc) {
            short8 af[4], bfr[2];
            #pragma unroll
            for (int mi = 0; mi < 4; ++mi)
                af[mi] = *(const short8*)&Xs[(wm + mi * 16 + lr) * 72 + kc * 32 + lk * 8];
            #pragma unroll
            for (int ni = 0; ni < 2; ++ni)
                bfr[ni] = *(const short8*)&Ws[(wn + ni * 16 + lr) * 72 + kc * 32 + lk * 8];
            #pragma unroll
            for (int mi = 0; mi < 4; ++mi)
                #pragma unroll
                for (int ni = 0; ni < 2; ++ni)
                    acc[mi][ni] = __builtin_amdgcn_mfma_f32_16x16x32_bf16(af[mi], bfr[ni], acc[mi][ni], 0, 0, 0);
        }
        __syncthreads();
    }
    #pragma unroll
    for (int mi = 0; mi < 4; ++mi)
        #pragma unroll
        for (int ni = 0; ni < 2; ++ni) {
            const int c = c0 + wn + ni * 16 + lr;
            const float bv2 = bias[c];
            #pragma unroll
            for (int i = 0; i < 4; ++i) {
                const int r = r0 + wm + mi * 16 + lk * 4 + i;
                Y[(size_t)r * DIM + c] = f2bf(silu_f(acc[mi][ni][i] + bv2));
            }
        }
}

// ---------------- k/q GEMM (elu+2): bx<64 phik; bx>=64 phiq. f32 weights. ----
__global__ __launch_bounds__(256) void gemm_kq(
        const short* __restrict__ H, const float* __restrict__ Wkf, const float* __restrict__ bk, short* __restrict__ PK,
        const float* __restrict__ Wqf, const float* __restrict__ bq, short* __restrict__ PQ) {
    __shared__ __align__(16) short Xs[128 * 72];
    __shared__ __align__(16) short Ws[64 * 72];
    const int bx = blockIdx.x;
    const bool isq = bx >= 64;
    const float* Wf = isq ? Wqf : Wkf;
    const float* bias = isq ? bq : bk;
    short* Y = isq ? PQ : PK;
    const int r0 = (isq ? bx - 64 : bx) * 128;
    const int c0 = blockIdx.y * 64;
    const int tid = threadIdx.x;
    const int wv = tid >> 6, l = tid & 63;
    const int lr = l & 15, lk = l >> 4;
    const int wm = (wv >> 1) * 64, wn = (wv & 1) * 32;
    f32x4 acc[4][2];
    #pragma unroll
    for (int i = 0; i < 4; ++i)
        #pragma unroll
        for (int j = 0; j < 2; ++j) acc[i][j] = (f32x4){0.f, 0.f, 0.f, 0.f};
    const int sr = tid >> 3, sc = (tid & 7) * 8;
    for (int kt = 0; kt < DIM; kt += 64) {
        #pragma unroll
        for (int p = 0; p < 4; ++p) {
            const int row = sr + p * 32;
            int grow = r0 + row;
            if (isq) grow = ((grow >> 8) << 12) + (grow & 255);
            *(short8*)&Xs[row * 72 + sc] = *(const short8*)(H + (size_t)grow * DIM + kt + sc);
        }
        #pragma unroll
        for (int p = 0; p < 2; ++p) {
            const int row = sr + p * 32;
            *(short8*)&Ws[row * 72 + sc] = cvt8(Wf + (size_t)(c0 + row) * DIM + kt + sc);
        }
        __syncthreads();
        #pragma unroll
        for (int kc = 0; kc < 2; ++kc) {
            short8 af[4], bfr[2];
            #pragma unroll
            for (int mi = 0; mi < 4; ++mi)
                af[mi] = *(const short8*)&Xs[(wm + mi * 16 + lr) * 72 + kc * 32 + lk * 8];
            #pragma unroll
            for (int ni = 0; ni < 2; ++ni)
                bfr[ni] = *(const short8*)&Ws[(wn + ni * 16 + lr) * 72 + kc * 32 + lk * 8];
            #pragma unroll
            for (int mi = 0; mi < 4; ++mi)
                #pragma unroll
                for (int ni = 0; ni < 2; ++ni)
                    acc[mi][ni] = __builtin_amdgcn_mfma_f32_16x16x32_bf16(af[mi], bfr[ni], acc[mi][ni], 0, 0, 0);
        }
        __syncthreads();
    }
    #pragma unroll
    for (int mi = 0; mi < 4; ++mi)
        #pragma unroll
        for (int ni = 0; ni < 2; ++ni) {
            const int c = c0 + wn + ni * 16 + lr;
            const float bv = bias[c];
            #pragma unroll
            for (int i = 0; i < 4; ++i) {
                const int r = r0 + wm + mi * 16 + lk * 4 + i;
                Y[(size_t)r * DIM + c] = f2bf(elu2_f(acc[mi][ni][i] + bv));
            }
        }
}

// ---------------- KV: kvT[b][m][d][c] = sum_w h[t][d]*phik[t][c], t=w*16+m ---
__global__ __launch_bounds__(256) void kv_mfma(const short* __restrict__ HB, const short* __restrict__ PK,
                                               short* __restrict__ KVT) {
    __shared__ __align__(16) short Hs[64 * 68];
    __shared__ __align__(16) short Ps[64 * 68];
    const int tid = threadIdx.x;
    const int bm = blockIdx.x, b = bm >> 4, m = bm & 15;
    const int d0 = blockIdx.y * 64, c0 = blockIdx.z * 64;
    const int wv = tid >> 6, l = tid & 63;
    const int lr = l & 15, lk = l >> 4;
    const int wd = (wv >> 1) * 32, wc = (wv & 1) * 32;
    f32x4 acc[2][2];
    #pragma unroll
    for (int i = 0; i < 2; ++i)
        #pragma unroll
        for (int j = 0; j < 2; ++j) acc[i][j] = (f32x4){0.f, 0.f, 0.f, 0.f};
    const size_t hbase = (size_t)b * NTOK * DIM;
    const int sr = tid >> 3, sc = (tid & 7) * 8;
    for (int kt = 0; kt < 256; kt += 64) {
        #pragma unroll
        for (int p = 0; p < 2; ++p) {
            const int w = sr + p * 32;
            const size_t gg = hbase + (size_t)((kt + w) * 16 + m) * DIM;
            short8 hv = *(const short8*)(HB + gg + d0 + sc);
            short8 pv = *(const short8*)(PK + gg + c0 + sc);
            *(short4v*)&Hs[w * 68 + sc]     = __builtin_shufflevector(hv, hv, 0, 1, 2, 3);
            *(short4v*)&Hs[w * 68 + sc + 4] = __builtin_shufflevector(hv, hv, 4, 5, 6, 7);
            *(short4v*)&Ps[w * 68 + sc]     = __builtin_shufflevector(pv, pv, 0, 1, 2, 3);
            *(short4v*)&Ps[w * 68 + sc + 4] = __builtin_shufflevector(pv, pv, 4, 5, 6, 7);
        }
        __syncthreads();
        #pragma unroll
        for (int kc = 0; kc < 2; ++kc) {
            const int kb = kc * 32 + lk * 8;
            short8 af[2], bfr[2];
            #pragma unroll
            for (int di = 0; di < 2; ++di)
                #pragma unroll
                for (int i = 0; i < 8; ++i)
                    af[di][i] = Hs[(kb + i) * 68 + wd + di * 16 + lr];
            #pragma unroll
            for (int ci = 0; ci < 2; ++ci)
                #pragma unroll
                for (int i = 0; i < 8; ++i)
                    bfr[ci][i] = Ps[(kb + i) * 68 + wc + ci * 16 + lr];
            #pragma unroll
            for (int di = 0; di < 2; ++di)
                #pragma unroll
                for (int ci = 0; ci < 2; ++ci)
                    acc[di][ci] = __builtin_amdgcn_mfma_f32_16x16x32_bf16(af[di], bfr[ci], acc[di][ci], 0, 0, 0);
        }
        __syncthreads();
    }
    #pragma unroll
    for (int di = 0; di < 2; ++di)
        #pragma unroll
        for (int ci = 0; ci < 2; ++ci)
            #pragma unroll
            for (int i = 0; i < 4; ++i) {
                const int d = d0 + wd + di * 16 + lk * 4 + i;
                const int c = c0 + wc + ci * 16 + lr;
                KVT[((size_t)bm * DIM + d) * DIM + c] = f2bf(acc[di][ci][i]);
            }
}

// ---------------- attlin: per (b,m,q-chunk of 32 rows):
// AG = (phiq @ kvT^T + p) * act_res  (to LDS bf16), then
// hid = AG @ Wl^T + bl + h  -> final LN -> out. --------------------------------
__global__ __launch_bounds__(256) void attlin(
        const short* __restrict__ PQ, const short* __restrict__ KVT,
        const float* __restrict__ emb, const float* __restrict__ pw, const float* __restrict__ pb,
        const short* __restrict__ AR,
        const float* __restrict__ WLf, const float* __restrict__ bl,
        const short* __restrict__ HB, const float* __restrict__ G, const float* __restrict__ Bt,
        float* __restrict__ Y) {
    __shared__ __align__(16) short Qs[32 * 264];
    __shared__ __align__(16) short AGs[32 * 264];
    __shared__ __align__(16) short Bs[256 * 72];
    __shared__ float s1buf[32][2];
    __shared__ float s2buf[32][2];
    const int tid = threadIdx.x;
    const int wv = tid >> 6, l = tid & 63;
    const int lr = l & 15, lk = l >> 4;
    const int bm = blockIdx.x, b = bm >> 4, m = bm & 15;
    const int q0 = blockIdx.y * 32;
    const int wq = (wv >> 1) * 16;   // q-row base within tile
    const int wd = (wv & 1) * 32;    // phase-A d base within each 64-chunk
    const int sr = tid >> 3, sc = (tid & 7) * 8;

    // load Q tile (32 rows x 256 c)
    #pragma unroll
    for (int p = 0; p < 4; ++p) {
        const int chunk = tid + p * 256;
        const int row = chunk >> 5, cc = (chunk & 31) * 8;
        *(short8*)&Qs[row * 264 + cc] = *(const short8*)(PQ + (size_t)(b * 256 + q0 + row) * DIM + cc);
    }

    // ---- phase A: AG = phiq @ kvT^T ----
    f32x4 accA[4][2];
    #pragma unroll
    for (int i = 0; i < 4; ++i)
        #pragma unroll
        for (int j = 0; j < 2; ++j) accA[i][j] = (f32x4){0.f, 0.f, 0.f, 0.f};
    for (int kt = 0; kt < DIM; kt += 64) {
        #pragma unroll
        for (int p = 0; p < 8; ++p) {
            const int row = sr + p * 32;  // d row
            *(short8*)&Bs[row * 72 + sc] = *(const short8*)(KVT + ((size_t)bm * DIM + row) * DIM + kt + sc);
        }
        __syncthreads();
        #pragma unroll
        for (int kc = 0; kc < 2; ++kc) {
            const short8 af = *(const short8*)&Qs[(wq + lr) * 264 + kt + kc * 32 + lk * 8];
            #pragma unroll
            for (int dc = 0; dc < 4; ++dc)
                #pragma unroll
                for (int ni = 0; ni < 2; ++ni) {
                    const short8 bfr = *(const short8*)&Bs[(dc * 64 + wd + ni * 16 + lr) * 72 + kc * 32 + lk * 8];
                    accA[dc][ni] = __builtin_amdgcn_mfma_f32_16x16x32_bf16(af, bfr, accA[dc][ni], 0, 0, 0);
                }
        }
        __syncthreads();
    }
    // phase A epilogue: +p, *act_res, -> AGs bf16
    {
        const float pw0 = pw[0], pw1 = pw[1], pw2 = pw[2], pbv = pb[0];
        #pragma unroll
        for (int i = 0; i < 4; ++i) {
            const int rloc = wq + lk * 4 + i;
            const int qr = q0 + rloc;
            const int widx = qr >> 4, nidx = qr & 15;
            const float* e = emb + ((((size_t)(2 + b) * 256 + widx) * 16 + nidx) * 16 + m) * 3;
            const float pv = e[0] * pw0 + e[1] * pw1 + e[2] * pw2 + pbv;
            const int t = qr * 16 + m;
            #pragma unroll
            for (int dc = 0; dc < 4; ++dc)
                #pragma unroll
                for (int ni = 0; ni < 2; ++ni) {
                    const int d = dc * 64 + wd + ni * 16 + lr;
                    const size_t o = ((size_t)b * NTOK + t) * DIM + d;
                    AGs[rloc * 264 + d] = f2bf((accA[dc][ni][i] + pv) * bf2f(AR[o]));
                }
        }
    }
    __syncthreads();

    // ---- phase B: hid = AG @ Wl^T + bl + residual; final LN ----
    const int wn2 = (wv & 1) * 128;
    f32x4 accB[8];
    #pragma unroll
    for (int i = 0; i < 8; ++i) accB[i] = (f32x4){0.f, 0.f, 0.f, 0.f};
    for (int kt = 0; kt < DIM; kt += 64) {
        #pragma unroll
        for (int p = 0; p < 8; ++p) {
            const int row = sr + p * 32;  // n row of Wl
            *(short8*)&Bs[row * 72 + sc] = cvt8(WLf + (size_t)row * DIM + kt + sc);
        }
        __syncthreads();
        #pragma unroll
        for (int kc = 0; kc < 2; ++kc) {
            const short8 af = *(const short8*)&AGs[(wq + lr) * 264 + kt + kc * 32 + lk * 8];
            #pragma unroll
            for (int ni = 0; ni < 8; ++ni) {
                const short8 bfr = *(const short8*)&Bs[(wn2 + ni * 16 + lr) * 72 + kc * 32 + lk * 8];
                accB[ni] = __builtin_amdgcn_mfma_f32_16x16x32_bf16(af, bfr, accB[ni], 0, 0, 0);
            }
        }
        __syncthreads();
    }
    // bias + residual; register LN stats
    float s1[4] = {0.f, 0.f, 0.f, 0.f}, s2[4] = {0.f, 0.f, 0.f, 0.f};
    #pragma unroll
    for (int ni = 0; ni < 8; ++ni) {
        const int col = wn2 + ni * 16 + lr;
        const float bv = bl[col];
        #pragma unroll
        for (int i = 0; i < 4; ++i) {
            const int rloc = wq + lk * 4 + i;
            const int t = (q0 + rloc) * 16 + m;
            const float z = accB[ni][i] + bv + bf2f(HB[((size_t)b * NTOK + t) * DIM + col]);
            accB[ni][i] = z;
            s1[i] += z; s2[i] += z * z;
        }
    }
    #pragma unroll
    for (int o = 1; o < 16; o <<= 1) {
        #pragma unroll
        for (int i = 0; i < 4; ++i) {
            s1[i] += __shfl_xor(s1[i], o);
            s2[i] += __shfl_xor(s2[i], o);
        }
    }
    if (lr == 0) {
        #pragma unroll
        for (int i = 0; i < 4; ++i) {
            const int rloc = wq + lk * 4 + i;
            s1buf[rloc][wv & 1] = s1[i];
            s2buf[rloc][wv & 1] = s2[i];
        }
    }
    __syncthreads();
    float mean[4], rstd[4];
    #pragma unroll
    for (int i = 0; i < 4; ++i) {
        const int rloc = wq + lk * 4 + i;
        const float t1 = s1buf[rloc][0] + s1buf[rloc][1];
        const float t2 = s2buf[rloc][0] + s2buf[rloc][1];
        const float mm = t1 * (1.f / DIM);
        mean[i] = mm;
        rstd[i] = rsqrtf(t2 * (1.f / DIM) - mm * mm + 1e-5f);
    }
    #pragma unroll
    for (int ni = 0; ni < 8; ++ni) {
        const int col = wn2 + ni * 16 + lr;
        const float gv = G[col], bv2 = Bt[col];
        #pragma unroll
        for (int i = 0; i < 4; ++i) {
            const int rloc = wq + lk * 4 + i;
            const int t = (q0 + rloc) * 16 + m;
            Y[((size_t)b * NTOK + t) * DIM + col] = (accB[ni][i] - mean[i]) * rstd[i] * gv + bv2;
        }
    }
}

extern "C" void kernel_launch(void* const* d_in, const int* in_sizes, int n_in,
                              void* d_out, int out_size, void* d_ws, size_t ws_size,
                              hipStream_t stream) {
    const float* x   = (const float*)d_in[0];
    const float* emb = (const float*)d_in[1];
    const float* Wa  = (const float*)d_in[2];
    const float* ba  = (const float*)d_in[3];
    const float* lng = (const float*)d_in[4];
    const float* lnb = (const float*)d_in[5];
    const float* Wc  = (const float*)d_in[6];
    const float* bc  = (const float*)d_in[7];
    const float* Wq  = (const float*)d_in[8];
    const float* bq  = (const float*)d_in[9];
    const float* Wk  = (const float*)d_in[10];
    const float* bk  = (const float*)d_in[11];
    const float* pw  = (const float*)d_in[12];
    const float* pb  = (const float*)d_in[13];
    const float* Wl  = (const float*)d_in[14];
    const float* bl  = (const float*)d_in[15];
    const float* ng  = (const float*)d_in[16];
    const float* nb  = (const float*)d_in[17];

    char* ws = (char*)d_ws;
    const size_t MB = 1024 * 1024;
    short* h_bf   = (short*)(ws + 0 * MB);    // 4 MB
    short* phik   = (short*)(ws + 4 * MB);    // 4 MB
    short* phiq   = (short*)(ws + 8 * MB);    // 256 KB
    short* kvT    = (short*)(ws + 9 * MB);    // 4 MB  [9,13)
    short* act_bf = (short*)(ws + 13 * MB);   // 4 MB  [13,17)

    const dim3 blk(256);
    fused_dual<<<dim3(64, 4, 2), blk, 0, stream>>>(x, Wa, ba, act_bf, Wc, bc, h_bf, lng, lnb);
    gemm_kq<<<dim3(68, 4), blk, 0, stream>>>(h_bf, Wk, bk, phik, Wq, bq, phiq);
    kv_mfma<<<dim3(32, 4, 4), blk, 0, stream>>>(h_bf, phik, kvT);
    attlin<<<dim3(32, 8), blk, 0, stream>>>(phiq, kvT, emb, pw, pb, act_bf, Wl, bl,
                                            h_bf, ng, nb, (float*)d_out);
}